// Round 2
// baseline (317.747 us; speedup 1.0000x reference)
//
#include <hip/hip_runtime.h>
#include <math.h>
#include <utility>

// B=16, T=16, FDIM=64, ODIM=8, NQ=10, NA=4, LAYERS=2, DEGREE=3.
// State: float2 state[b][a][n], n<1024 (qubit i <-> bit 9-i of n), a<16
// (ancilla qubit NQ+qi <-> bit 3-qi of a).
// Wave-resident select: one 64-lane wave owns one (b,a) column.
// Amp mapping: n = lane*16 + r  (bits [3:0]=r in-thread, [9:4]=lane).
// Gates on bit<4: thread-local. Gates on bit>=4: __shfl_xor butterfly.
//
// FUSED, SINGLE NORMAL DISPATCH: 256 blocks x 64 lanes (one wave each; all
// 256 waves are trivially co-resident on 256 CUs, so a manual spin barrier
// cannot deadlock). Grid sync = sense-reversing barrier on __device__
// globals with agent-scope atomics + __threadfence() on both sides
// (explicit cross-XCD L2 writeback/invalidate). No cooperative launch,
// no hipGraph-capture hazards.

struct Gate { int ry; int tbit; int cbit; int pidx; };
struct GateTab { Gate g[40]; };

constexpr GateTab make_gates1() {
  GateTab tb{};
  int pos = 0, idx = 0;
  for (int i = 0; i < 10; ++i) { tb.g[pos] = Gate{1, 9 - i, -1, idx}; ++pos; ++idx; }
  for (int i = 9; i >= 0; --i) { tb.g[pos] = Gate{0, 9 - ((i + 1) % 10), 9 - i, idx}; ++pos; ++idx; }
  for (int i = 0; i < 10; ++i) { tb.g[pos] = Gate{1, 9 - i, -1, idx}; ++pos; ++idx; }
  for (int k = 0; k < 10; ++k) {
    int i = (k == 0) ? 9 : (k - 1);
    tb.g[pos] = Gate{0, 9 - ((i + 9) % 10), 9 - i, idx}; ++pos; ++idx;
  }
  return tb;
}
constexpr GateTab GTC = make_gates1();

__device__ __forceinline__ int insert_zero(int v, int p) {
  return ((v >> p) << (p + 1)) | (v & ((1 << p) - 1));
}
__device__ __forceinline__ float2 cmul(float2 A, float2 B) {
  return make_float2(A.x * B.x - A.y * B.y, A.x * B.y + A.y * B.x);
}
__device__ __forceinline__ float2 conj2(float2 A) { return make_float2(A.x, -A.y); }
__device__ __forceinline__ float2 cfma(float2 A, float2 B, float2 acc) {
  acc.x += A.x * B.x - A.y * B.y;
  acc.y += A.x * B.y + A.y * B.x;
  return acc;
}

// ---------------- manual grid barrier (sense-reversing) ----------------
// State persists across launches: each barrier leaves cnt=0, gen+1.
// Zero-initialized at module load; never touched by workspace poison.
__device__ unsigned g_bar_cnt = 0;
__device__ unsigned g_bar_gen = 0;

__device__ __forceinline__ void grid_barrier() {
  __threadfence();                 // release: L2 writeback (all lanes, wave-uniform)
  __syncthreads();
  if (threadIdx.x == 0) {
    unsigned gen = __hip_atomic_load(&g_bar_gen, __ATOMIC_RELAXED, __HIP_MEMORY_SCOPE_AGENT);
    unsigned arrived =
        __hip_atomic_fetch_add(&g_bar_cnt, 1u, __ATOMIC_ACQ_REL, __HIP_MEMORY_SCOPE_AGENT) + 1u;
    if (arrived == 256u) {
      __hip_atomic_store(&g_bar_cnt, 0u, __ATOMIC_RELAXED, __HIP_MEMORY_SCOPE_AGENT);
      __hip_atomic_store(&g_bar_gen, gen + 1u, __ATOMIC_RELEASE, __HIP_MEMORY_SCOPE_AGENT);
    } else {
      while (__hip_atomic_load(&g_bar_gen, __ATOMIC_ACQUIRE, __HIP_MEMORY_SCOPE_AGENT) == gen)
        __builtin_amdgcn_s_sleep(1);
    }
  }
  __syncthreads();
  __threadfence();                 // acquire: invalidate stale L2 lines before re-reads
}

// ---------------- register/shuffle gate engine ----------------
template<int P>
__device__ __forceinline__ void ry_gate(float2 (&a)[16], float c, float s, int lane) {
  if constexpr (P < 4) {
    constexpr int m = 1 << P;
#pragma unroll
    for (int r0 = 0; r0 < 16; ++r0) {
      if (!(r0 & m)) {
        int r1 = r0 | m;
        float2 a0 = a[r0], a1 = a[r1];
        a[r0] = make_float2(c * a0.x - s * a1.x, c * a0.y - s * a1.y);
        a[r1] = make_float2(s * a0.x + c * a1.x, s * a0.y + c * a1.y);
      }
    }
  } else {
    constexpr int xm = 1 << (P - 4);
    bool up = (lane >> (P - 4)) & 1;
    float sg = up ? s : -s;
#pragma unroll
    for (int r = 0; r < 16; ++r) {
      float wx = __shfl_xor(a[r].x, xm, 64);
      float wy = __shfl_xor(a[r].y, xm, 64);
      a[r].x = c * a[r].x + sg * wx;
      a[r].y = c * a[r].y + sg * wy;
    }
  }
}

template<int P, int Q>
__device__ __forceinline__ void crx_gate(float2 (&a)[16], float c, float s, int lane) {
  if constexpr (P < 4) {
    constexpr int m = 1 << P;
#pragma unroll
    for (int r0 = 0; r0 < 16; ++r0) {
      if (!(r0 & m)) {
        int r1 = r0 | m;
        bool act;
        if constexpr (Q < 4) act = (r0 >> Q) & 1;
        else act = (lane >> (Q - 4)) & 1;
        if (act) {
          float2 a0 = a[r0], a1 = a[r1];
          a[r0] = make_float2(c * a0.x + s * a1.y, c * a0.y - s * a1.x);
          a[r1] = make_float2(c * a1.x + s * a0.y, c * a1.y - s * a0.x);
        }
      }
    }
  } else {
    constexpr int xm = 1 << (P - 4);
#pragma unroll
    for (int r = 0; r < 16; ++r) {
      float wx = __shfl_xor(a[r].x, xm, 64);
      float wy = __shfl_xor(a[r].y, xm, 64);
      bool act;
      if constexpr (Q < 4) act = (r >> Q) & 1;
      else act = (lane >> (Q - 4)) & 1;
      if (act) {
        float nx = c * a[r].x + s * wy;
        float ny = c * a[r].y - s * wx;
        a[r].x = nx; a[r].y = ny;
      }
    }
  }
}

template<bool ADJ, int G>
__device__ __forceinline__ void one_gate(float2 (&a)[16], const float2* sc, int lane) {
  constexpr Gate g = GTC.g[ADJ ? (39 - G) : G];
  float2 scv = sc[g.pidx];
  float s = ADJ ? -scv.x : scv.x;
  float c = scv.y;
  if constexpr (g.ry != 0) ry_gate<g.tbit>(a, c, s, lane);
  else crx_gate<g.tbit, g.cbit>(a, c, s, lane);
}

template<bool ADJ, int... I>
__device__ __forceinline__ void run_layer_impl(float2 (&a)[16], const float2* sc,
                                               int lane, std::integer_sequence<int, I...>) {
  (one_gate<ADJ, I>(a, sc, lane), ...);
}
template<bool ADJ>
__device__ __forceinline__ void run_layer(float2 (&a)[16], const float2* sc, int lane) {
  run_layer_impl<ADJ>(a, sc, lane, std::make_integer_sequence<int, 40>{});
}

// Mix using a single LDS-resident matrix row: a[r] = sum_ap Mrow[ap]*src[b][ap][lane*16+r]
__device__ __forceinline__ void mix_load_row(float2 (&a)[16], const float2* __restrict__ src,
                                             const float2* Mrow, int b, int lane) {
#pragma unroll
  for (int r = 0; r < 16; ++r) a[r] = make_float2(0.f, 0.f);
#pragma unroll
  for (int ap = 0; ap < 16; ++ap) {
    float2 m = Mrow[ap];
    const float4* col4 = (const float4*)(src + (size_t)(b * 16 + ap) * 1024) + lane * 8;
#pragma unroll
    for (int q = 0; q < 8; ++q) {
      float4 v = col4[q];
      a[2 * q].x     += m.x * v.x - m.y * v.y;
      a[2 * q].y     += m.x * v.y + m.y * v.x;
      a[2 * q + 1].x += m.x * v.z - m.y * v.w;
      a[2 * q + 1].y += m.x * v.w + m.y * v.z;
    }
  }
}

// Old-style mix (full matrix in global) for the fallback path.
__device__ __forceinline__ void mix_load(float2 (&a)[16], const float2* __restrict__ src,
                                         const float2* __restrict__ M, int b, int aa, int lane) {
#pragma unroll
  for (int r = 0; r < 16; ++r) a[r] = make_float2(0.f, 0.f);
#pragma unroll
  for (int ap = 0; ap < 16; ++ap) {
    float2 m = M[aa * 16 + ap];
    const float4* col4 = (const float4*)(src + (size_t)(b * 16 + ap) * 1024) + lane * 8;
#pragma unroll
    for (int q = 0; q < 8; ++q) {
      float4 v = col4[q];
      a[2 * q].x     += m.x * v.x - m.y * v.y;
      a[2 * q].y     += m.x * v.y + m.y * v.x;
      a[2 * q + 1].x += m.x * v.z - m.y * v.w;
      a[2 * q + 1].y += m.x * v.w + m.y * v.z;
    }
  }
}

__device__ __forceinline__ void store_col(float2* dst, int blk, int lane, float2 (&a)[16]) {
  float4* o4 = (float4*)(dst + (size_t)blk * 1024) + lane * 8;
#pragma unroll
  for (int q = 0; q < 8; ++q)
    o4[q] = make_float4(a[2 * q].x, a[2 * q].y, a[2 * q + 1].x, a[2 * q + 1].y);
}

// ---------------- the fused kernel (normal launch + manual barrier) ----------------
__global__ __launch_bounds__(64) void k_fused(const float* __restrict__ x,
                                              const float* __restrict__ W_fp,
                                              const float* __restrict__ b_fp,
                                              const float* __restrict__ prep,
                                              const float* __restrict__ sig,
                                              const float* __restrict__ qff,
                                              const float* __restrict__ W_out,
                                              const float* __restrict__ b_out,
                                              float* __restrict__ out,
                                              float2* __restrict__ state0,
                                              float2* __restrict__ state1,
                                              float* __restrict__ sv) {
  int blk = blockIdx.x, lane = threadIdx.x;     // blk = b*16 + a
  int b = blk >> 4, aa = blk & 15;

  __shared__ float h[64];
  __shared__ float2 U[256];                     // prepare unitary U[a*16 + j]
  __shared__ float2 scs[80];                    // ts (sin,cos) for this column (t = aa)
  __shared__ float2 qscs[40];                   // qff (sin,cos)
  __shared__ float2 m1row[16], m2row[16], mendrow[16];

  // ---- phase 0a: ts params for (b, t = aa) ----
  {
    int t = aa;
    int f = lane, k = f >> 1;
    float div = expf(-(float)(2 * k) * (logf(10000.f) / 64.f));
    float ang = (float)t * div;
    float pe = (f & 1) ? cosf(ang) : sinf(ang);
    h[f] = x[(b * 64 + f) * 16 + t] + pe;
    __syncthreads();
    for (int j = lane; j < 80; j += 64) {
      float acc = b_fp[j];
      const float* wr = W_fp + j * 64;
#pragma unroll 8
      for (int ff = 0; ff < 64; ++ff) acc += h[ff] * wr[ff];
      float sg = 1.f / (1.f + expf(-acc));
      float s, c;
      sincosf(sg * 3.14159265358979323846f, &s, &c);   // theta/2 = sigmoid*pi
      scs[j] = make_float2(s, c);
    }
  }

  // ---- phase 0b: build the 16x16 prepare unitary U (replicated per block) ----
  for (int it = lane; it < 256; it += 64)
    U[it] = make_float2((it >> 4) == (it & 15) ? 1.f : 0.f, 0.f);
  __syncthreads();
  for (int ly = 0; ly < 4; ++ly) {
    for (int qi = 0; qi < 4; ++qi) {
      int p = 3 - qi;
      float s, c;
      sincosf(0.5f * prep[ly * 8 + qi * 2 + 0], &s, &c);
      for (int it = lane; it < 128; it += 64) {
        int j = it & 15, pp = it >> 4;
        int a0 = insert_zero(pp, p), a1 = a0 | (1 << p);
        float2 u0 = U[a0 * 16 + j], u1 = U[a1 * 16 + j];
        U[a0 * 16 + j] = make_float2(c * u0.x - s * u1.x, c * u0.y - s * u1.y);
        U[a1 * 16 + j] = make_float2(s * u0.x + c * u1.x, s * u0.y + c * u1.y);
      }
      __syncthreads();
      sincosf(0.5f * prep[ly * 8 + qi * 2 + 1], &s, &c);
      for (int it = lane; it < 128; it += 64) {
        int j = it & 15, pp = it >> 4;
        int a0 = insert_zero(pp, p), a1 = a0 | (1 << p);
        float2 u0 = U[a0 * 16 + j], u1 = U[a1 * 16 + j];
        U[a0 * 16 + j] = make_float2(c * u0.x + s * u0.y, c * u0.y - s * u0.x);
        U[a1 * 16 + j] = make_float2(c * u1.x - s * u1.y, c * u1.y + s * u1.x);
      }
      __syncthreads();
    }
    for (int i = 0; i < 3; ++i) {
      int pc = 3 - i, pt = 2 - i;
      {
        int j = lane & 15, pp = lane >> 4;     // exactly 64 items
        int m = insert_zero(pp, pt);
        m = insert_zero(m, pc);
        int a0 = m | (1 << pc), a1 = a0 | (1 << pt);
        float2 t0 = U[a0 * 16 + j], t1 = U[a1 * 16 + j];
        U[a0 * 16 + j] = t1;
        U[a1 * 16 + j] = t0;
      }
      __syncthreads();
    }
  }

  // ---- phase 0c: per-block matrix rows + qsc + init scalar; zero sv ----
  float2 e0, e1, e2, e3;
  sincosf(sig[0], &e0.y, &e0.x);
  sincosf(sig[1], &e1.y, &e1.x);
  sincosf(sig[2], &e2.y, &e2.x);
  sincosf(sig[3], &e3.y, &e3.x);
  if (lane < 16) {
    float2 acc1 = make_float2(0.f, 0.f), acc2 = make_float2(0.f, 0.f);
    for (int cix = 0; cix < 16; ++cix) {
      float2 t = cmul(U[aa * 16 + cix], conj2(U[lane * 16 + cix]));
      acc1 = cfma(t, (cix == 0) ? e1 : conj2(e1), acc1);
      acc2 = cfma(t, (cix == 0) ? e2 : conj2(e2), acc2);
    }
    m1row[lane] = acc1;                         // (U D1 U^dag)[aa][lane]
    m2row[lane] = acc2;                         // (U D2 U^dag)[aa][lane]
    float2 v3 = (aa == 0) ? e3 : conj2(e3);
    mendrow[lane] = cmul(v3, conj2(U[lane * 16 + aa]));   // (D3 U^dag)[aa][lane]
  }
  if (lane < 40) {
    float s, c;
    sincosf(0.5f * qff[lane], &s, &c);
    qscs[lane] = make_float2(s, c);
  }
  float2 m0 = cmul(U[aa * 16 + 0], e0);         // (U D0)[aa][0] * e^{i sig0}
  if (blk == 255) {
    for (int j = lane; j < 480; j += 64) sv[j] = 0.f;   // flushed by barrier-1 release
  }
  __syncthreads();

  const float2* sc = scs;
  float2 a[16];

  // ---- phase 1: init |0..0> column + select fwd ----
#pragma unroll
  for (int r = 0; r < 16; ++r) a[r] = make_float2(0.f, 0.f);
  if (lane == 0) a[0] = m0;
  run_layer<false>(a, sc, lane);
  run_layer<false>(a, sc + 40, lane);
  store_col(state0, blk, lane, a);
  grid_barrier();

  // ---- phase 2: mix M1 + select adjoint ----
  mix_load_row(a, state0, m1row, b, lane);
  run_layer<true>(a, sc + 40, lane);
  run_layer<true>(a, sc, lane);
  store_col(state1, blk, lane, a);
  grid_barrier();

  // ---- phase 3: mix M2 + select fwd ----
  mix_load_row(a, state1, m2row, b, lane);
  run_layer<false>(a, sc, lane);
  run_layer<false>(a, sc + 40, lane);
  store_col(state0, blk, lane, a);
  grid_barrier();

  // ---- phase 4: mix Mend + qff + expvals partials ----
  mix_load_row(a, state0, mendrow, b, lane);
  run_layer<false>(a, qscs, lane);
  {
    float obs[30];
#pragma unroll
    for (int p = 0; p <= 9; ++p) {
      int i = 9 - p;
      float cr = 0.f, ci = 0.f, zz = 0.f;
      if (p < 4) {
        int m = 1 << p;
#pragma unroll
        for (int r0 = 0; r0 < 16; ++r0) {
          if (!(r0 & m)) {
            float2 A0 = a[r0], A1 = a[r0 | m];
            cr += A0.x * A1.x + A0.y * A1.y;
            ci += A0.x * A1.y - A0.y * A1.x;
            zz += (A0.x * A0.x + A0.y * A0.y) - (A1.x * A1.x + A1.y * A1.y);
          }
        }
      } else {
        int xm = 1 << (p - 4);
        bool up = (lane >> (p - 4)) & 1;
#pragma unroll
        for (int r = 0; r < 16; ++r) {
          float wx = __shfl_xor(a[r].x, xm, 64);
          float wy = __shfl_xor(a[r].y, xm, 64);
          float n2 = a[r].x * a[r].x + a[r].y * a[r].y;
          if (!up) {
            cr += a[r].x * wx + a[r].y * wy;
            ci += a[r].x * wy - a[r].y * wx;
            zz += n2;
          } else {
            zz -= n2;
          }
        }
      }
      obs[i] = 2.f * cr;
      obs[10 + i] = 2.f * ci;
      obs[20 + i] = zz;
    }
#pragma unroll
    for (int j = 0; j < 30; ++j) {
      float v = obs[j];
      for (int off = 32; off; off >>= 1) v += __shfl_down(v, off, 64);
      if (lane == 0) atomicAdd(&sv[b * 30 + j], v);
    }
  }
  grid_barrier();

  // ---- phase 5: output layer (block 0) ----
  if (blk == 0) {
    for (int tid = lane; tid < 128; tid += 64) {
      int bb = tid >> 3, o = tid & 7;
      float acc = b_out[o];
#pragma unroll
      for (int j = 0; j < 30; ++j) acc += W_out[o * 30 + j] * sv[bb * 30 + j];
      out[tid] = acc;
    }
  }
}

// ================= fallback multi-kernel path (ws too small) =================

__global__ __launch_bounds__(128) void k_ts(const float* __restrict__ x,
                                            const float* __restrict__ W,
                                            const float* __restrict__ bias,
                                            float2* __restrict__ tsc) {
  int blk = blockIdx.x;
  int b = blk >> 4, t = blk & 15;
  __shared__ float h[64];
  int tid = threadIdx.x;
  if (tid < 64) {
    int f = tid, k = f >> 1;
    float div = expf(-(float)(2 * k) * (logf(10000.f) / 64.f));
    float ang = (float)t * div;
    float pe = (f & 1) ? cosf(ang) : sinf(ang);
    h[f] = x[(b * 64 + f) * 16 + t] + pe;
  }
  __syncthreads();
  if (tid < 80) {
    float acc = bias[tid];
    const float* wr = W + tid * 64;
#pragma unroll 8
    for (int f = 0; f < 64; ++f) acc += h[f] * wr[f];
    float sg = 1.f / (1.f + expf(-acc));
    float s, c;
    sincosf(sg * 3.14159265358979323846f, &s, &c);
    tsc[blk * 80 + tid] = make_float2(s, c);
  }
}

__global__ __launch_bounds__(256) void k_build(const float* __restrict__ prep,
                                               const float* __restrict__ sig,
                                               const float* __restrict__ qffp,
                                               float2* __restrict__ mats,
                                               float2* __restrict__ qsc) {
  __shared__ float2 U[256];
  int tid = threadIdx.x;
  if (tid < 40) {
    float s, c;
    sincosf(0.5f * qffp[tid], &s, &c);
    qsc[tid] = make_float2(s, c);
  }
  U[tid] = make_float2((tid >> 4) == (tid & 15) ? 1.f : 0.f, 0.f);
  __syncthreads();
  for (int ly = 0; ly < 4; ++ly) {
    for (int qi = 0; qi < 4; ++qi) {
      int p = 3 - qi;
      float th = prep[ly * 8 + qi * 2 + 0];
      float s, c;
      sincosf(0.5f * th, &s, &c);
      if (tid < 128) {
        int j = tid & 15, pp = tid >> 4;
        int a0 = insert_zero(pp, p), a1 = a0 | (1 << p);
        float2 u0 = U[a0 * 16 + j], u1 = U[a1 * 16 + j];
        U[a0 * 16 + j] = make_float2(c * u0.x - s * u1.x, c * u0.y - s * u1.y);
        U[a1 * 16 + j] = make_float2(s * u0.x + c * u1.x, s * u0.y + c * u1.y);
      }
      __syncthreads();
      th = prep[ly * 8 + qi * 2 + 1];
      sincosf(0.5f * th, &s, &c);
      if (tid < 128) {
        int j = tid & 15, pp = tid >> 4;
        int a0 = insert_zero(pp, p), a1 = a0 | (1 << p);
        float2 u0 = U[a0 * 16 + j], u1 = U[a1 * 16 + j];
        U[a0 * 16 + j] = make_float2(c * u0.x + s * u0.y, c * u0.y - s * u0.x);
        U[a1 * 16 + j] = make_float2(c * u1.x - s * u1.y, c * u1.y + s * u1.x);
      }
      __syncthreads();
    }
    for (int i = 0; i < 3; ++i) {
      int pc = 3 - i, pt = 2 - i;
      if (tid < 64) {
        int j = tid & 15, pp = tid >> 4;
        int m = insert_zero(pp, pt);
        m = insert_zero(m, pc);
        int a0 = m | (1 << pc), a1 = a0 | (1 << pt);
        float2 t0 = U[a0 * 16 + j], t1 = U[a1 * 16 + j];
        U[a0 * 16 + j] = t1;
        U[a1 * 16 + j] = t0;
      }
      __syncthreads();
    }
  }
  int a = tid >> 4, bb = tid & 15;
  float2 e1, e2, e3;
  sincosf(sig[1], &e1.y, &e1.x);
  sincosf(sig[2], &e2.y, &e2.x);
  sincosf(sig[3], &e3.y, &e3.x);
  float2 acc1 = make_float2(0.f, 0.f), acc2 = make_float2(0.f, 0.f);
  for (int cix = 0; cix < 16; ++cix) {
    float2 t = cmul(U[a * 16 + cix], conj2(U[bb * 16 + cix]));
    acc1 = cfma(t, (cix == 0) ? e1 : conj2(e1), acc1);
    acc2 = cfma(t, (cix == 0) ? e2 : conj2(e2), acc2);
  }
  mats[16 + tid] = acc1;
  mats[272 + tid] = acc2;
  float2 v3 = (a == 0) ? e3 : conj2(e3);
  mats[528 + tid] = cmul(v3, conj2(U[bb * 16 + a]));
  if (tid < 16) {
    float2 e0;
    sincosf(sig[0], &e0.y, &e0.x);
    mats[tid] = cmul(U[tid * 16 + 0], e0);
  }
}

template<bool ADJ, int MODE>
__global__ __launch_bounds__(64) void k_sel(const float2* __restrict__ src,
                                            float2* __restrict__ dst,
                                            const float2* __restrict__ sc_ts,
                                            const float2* __restrict__ mat) {
  int blk = blockIdx.x, lane = threadIdx.x;
  const float2* __restrict__ sc = sc_ts + blk * 80;
  float2 a[16];
  if constexpr (MODE == 0) {
#pragma unroll
    for (int r = 0; r < 16; ++r) a[r] = make_float2(0.f, 0.f);
    if (lane == 0) a[0] = mat[blk & 15];
  } else if constexpr (MODE == 1) {
    const float4* g4 = (const float4*)(src + (size_t)blk * 1024) + lane * 8;
#pragma unroll
    for (int q = 0; q < 8; ++q) {
      float4 v = g4[q];
      a[2 * q]     = make_float2(v.x, v.y);
      a[2 * q + 1] = make_float2(v.z, v.w);
    }
  } else {
    mix_load(a, src, mat, blk >> 4, blk & 15, lane);
  }
  if constexpr (ADJ) {
    run_layer<true>(a, sc + 40, lane);
    run_layer<true>(a, sc, lane);
  } else {
    run_layer<false>(a, sc, lane);
    run_layer<false>(a, sc + 40, lane);
  }
  store_col(dst, blk, lane, a);
}

__global__ __launch_bounds__(64) void k_qff_exp(const float2* __restrict__ src,
                                                const float2* __restrict__ mend,
                                                const float2* __restrict__ qsc,
                                                float* __restrict__ sv) {
  int blk = blockIdx.x, lane = threadIdx.x;
  int b = blk >> 4, aa = blk & 15;
  float2 a[16];
  mix_load(a, src, mend, b, aa, lane);
  run_layer<false>(a, qsc, lane);
  float obs[30];
#pragma unroll
  for (int p = 0; p <= 9; ++p) {
    int i = 9 - p;
    float cr = 0.f, ci = 0.f, zz = 0.f;
    if (p < 4) {
      int m = 1 << p;
#pragma unroll
      for (int r0 = 0; r0 < 16; ++r0) {
        if (!(r0 & m)) {
          float2 A0 = a[r0], A1 = a[r0 | m];
          cr += A0.x * A1.x + A0.y * A1.y;
          ci += A0.x * A1.y - A0.y * A1.x;
          zz += (A0.x * A0.x + A0.y * A0.y) - (A1.x * A1.x + A1.y * A1.y);
        }
      }
    } else {
      int xm = 1 << (p - 4);
      bool up = (lane >> (p - 4)) & 1;
#pragma unroll
      for (int r = 0; r < 16; ++r) {
        float wx = __shfl_xor(a[r].x, xm, 64);
        float wy = __shfl_xor(a[r].y, xm, 64);
        float n2 = a[r].x * a[r].x + a[r].y * a[r].y;
        if (!up) {
          cr += a[r].x * wx + a[r].y * wy;
          ci += a[r].x * wy - a[r].y * wx;
          zz += n2;
        } else {
          zz -= n2;
        }
      }
    }
    obs[i] = 2.f * cr;
    obs[10 + i] = 2.f * ci;
    obs[20 + i] = zz;
  }
#pragma unroll
  for (int j = 0; j < 30; ++j) {
    float v = obs[j];
    for (int off = 32; off; off >>= 1) v += __shfl_down(v, off, 64);
    if (lane == 0) atomicAdd(&sv[b * 30 + j], v);
  }
}

__global__ __launch_bounds__(128) void k_out(const float* __restrict__ sv,
                                             const float* __restrict__ W,
                                             const float* __restrict__ bo,
                                             float* __restrict__ out) {
  int tid = threadIdx.x;
  int b = tid >> 3, o = tid & 7;
  float acc = bo[o];
#pragma unroll
  for (int j = 0; j < 30; ++j) acc += W[o * 30 + j] * sv[b * 30 + j];
  out[tid] = acc;
}

__global__ __launch_bounds__(256) void k_anc(float2* __restrict__ state,
                                             const float2* __restrict__ M) {
  __shared__ float2 sM[256];
  int tid = threadIdx.x;
  sM[tid] = M[tid];
  __syncthreads();
  int t = blockIdx.x * 256 + tid;
  int b = t >> 10, n = t & 1023;
  float2* p = state + b * 16384 + n;
  float2 v[16];
#pragma unroll
  for (int ap = 0; ap < 16; ++ap) v[ap] = p[ap << 10];
#pragma unroll
  for (int ao = 0; ao < 16; ++ao) {
    float re = 0.f, im = 0.f;
#pragma unroll
    for (int ap = 0; ap < 16; ++ap) {
      float2 m = sM[ao * 16 + ap];
      re += m.x * v[ap].x - m.y * v[ap].y;
      im += m.x * v[ap].y + m.y * v[ap].x;
    }
    p[ao << 10] = make_float2(re, im);
  }
}

extern "C" void kernel_launch(void* const* d_in, const int* in_sizes, int n_in,
                              void* d_out, int out_size, void* d_ws, size_t ws_size,
                              hipStream_t stream) {
  const float* x     = (const float*)d_in[0];
  const float* W_fp  = (const float*)d_in[1];
  const float* b_fp  = (const float*)d_in[2];
  const float* prep  = (const float*)d_in[3];
  const float* sig   = (const float*)d_in[4];
  const float* qff   = (const float*)d_in[5];
  const float* W_out = (const float*)d_in[6];
  const float* b_out = (const float*)d_in[7];
  float* out = (float*)d_out;

  char* ws = (char*)d_ws;
  const size_t SZ_STATE = 2097152;      // 256 cols * 1024 * 8 B
  const size_t SZ_SV    = 1920;         // 16*30 float

  if (ws_size >= 2 * SZ_STATE + SZ_SV) {
    // fused single-dispatch path (normal launch; manual grid barrier inside)
    float2* state0 = (float2*)ws;
    float2* state1 = (float2*)(ws + SZ_STATE);
    float*  sv     = (float*)(ws + 2 * SZ_STATE);
    k_fused<<<dim3(256), dim3(64), 0, stream>>>(x, W_fp, b_fp, prep, sig, qff,
                                                W_out, b_out, out, state0, state1, sv);
    return;
  }

  // fallback multi-kernel path (original structure)
  const size_t SZ_TSC   = 163840;
  const size_t SZ_MATS  = 6272;
  const size_t SZ_QSC   = 320;
  bool pp = ws_size >= 2 * SZ_STATE + SZ_TSC + SZ_MATS + SZ_QSC + SZ_SV;

  float2* state0 = (float2*)ws;
  float2* state1 = pp ? (float2*)(ws + SZ_STATE) : nullptr;
  char* tail = ws + (pp ? 2 * SZ_STATE : SZ_STATE);
  float2* tsc  = (float2*)tail;
  float2* mats = (float2*)(tail + SZ_TSC);
  float2* qsc  = (float2*)(tail + SZ_TSC + SZ_MATS);
  float*  sv   = (float*) (tail + SZ_TSC + SZ_MATS + SZ_QSC);

  hipMemsetAsync(sv, 0, SZ_SV, stream);
  k_ts<<<256, 128, 0, stream>>>(x, W_fp, b_fp, tsc);
  k_build<<<1, 256, 0, stream>>>(prep, sig, qff, mats, qsc);

  if (pp) {
    k_sel<false, 0><<<256, 64, 0, stream>>>(nullptr, state0, tsc, mats);
    k_sel<true,  2><<<256, 64, 0, stream>>>(state0, state1, tsc, mats + 16);
    k_sel<false, 2><<<256, 64, 0, stream>>>(state1, state0, tsc, mats + 272);
  } else {
    k_sel<false, 0><<<256, 64, 0, stream>>>(nullptr, state0, tsc, mats);
    k_anc<<<64, 256, 0, stream>>>(state0, mats + 16);
    k_sel<true,  1><<<256, 64, 0, stream>>>(state0, state0, tsc, nullptr);
    k_anc<<<64, 256, 0, stream>>>(state0, mats + 272);
    k_sel<false, 1><<<256, 64, 0, stream>>>(state0, state0, tsc, nullptr);
  }
  k_qff_exp<<<256, 64, 0, stream>>>(state0, mats + 528, qsc, sv);
  k_out<<<1, 128, 0, stream>>>(sv, W_out, b_out, out);
}

// Round 3
// 233.199 us; speedup vs baseline: 1.3626x; 1.3626x over previous
//
#include <hip/hip_runtime.h>
#include <math.h>
#include <utility>

// B=16, T=16, FDIM=64, ODIM=8, NQ=10, NA=4, LAYERS=2, DEGREE=3.
// State: float2 state[b][a][n], n<1024 (qubit i <-> bit 9-i of n), a<16
// (ancilla qubit NQ+qi <-> bit 3-qi of a).
// Wave-resident select: one 64-lane wave owns one (b,a) column.
// Amp mapping: n = lane*16 + r  (bits [3:0]=r in-thread, [9:4]=lane).
// Gates on bit<4: thread-local. Gates on bit>=4: __shfl_xor butterfly.
//
// FUSED, SINGLE NORMAL DISPATCH: 256 blocks x 64 lanes (one wave each).
// Cross-block sync is PER-B GROUPS OF 16 BLOCKS (the mix only reads the 16
// sibling columns of the same b), via monotonic count+gen words:
//   - arrival: one ACQ_REL fetch_add (release = L2 writeback of our column)
//   - wait:    RELAXED spin loads (NO cache maintenance per poll) + s_sleep
//   - exit:    one ACQUIRE load (single invalidate)
// This replaces round-2's global barrier whose per-poll acquire loads +
// seq_cst threadfences cost ~50us/barrier in L2-invalidate storms.
// Output row b is computed by the LAST-arriving block of group b (done
// counter), removing the 4th barrier + serial block-0 tail.

struct Gate { int ry; int tbit; int cbit; int pidx; };
struct GateTab { Gate g[40]; };

constexpr GateTab make_gates1() {
  GateTab tb{};
  int pos = 0, idx = 0;
  for (int i = 0; i < 10; ++i) { tb.g[pos] = Gate{1, 9 - i, -1, idx}; ++pos; ++idx; }
  for (int i = 9; i >= 0; --i) { tb.g[pos] = Gate{0, 9 - ((i + 1) % 10), 9 - i, idx}; ++pos; ++idx; }
  for (int i = 0; i < 10; ++i) { tb.g[pos] = Gate{1, 9 - i, -1, idx}; ++pos; ++idx; }
  for (int k = 0; k < 10; ++k) {
    int i = (k == 0) ? 9 : (k - 1);
    tb.g[pos] = Gate{0, 9 - ((i + 9) % 10), 9 - i, idx}; ++pos; ++idx;
  }
  return tb;
}
constexpr GateTab GTC = make_gates1();

__device__ __forceinline__ int insert_zero(int v, int p) {
  return ((v >> p) << (p + 1)) | (v & ((1 << p) - 1));
}
__device__ __forceinline__ float2 cmul(float2 A, float2 B) {
  return make_float2(A.x * B.x - A.y * B.y, A.x * B.y + A.y * B.x);
}
__device__ __forceinline__ float2 conj2(float2 A) { return make_float2(A.x, -A.y); }
__device__ __forceinline__ float2 cfma(float2 A, float2 B, float2 acc) {
  acc.x += A.x * B.x - A.y * B.y;
  acc.y += A.x * B.y + A.y * B.x;
  return acc;
}

// ---------------- per-b group barrier (16 participants) ----------------
// Monotonic words; zero-initialized at module load; never reset (mod-16
// round detection), so graph replay / multiple launches are safe.
struct alignas(128) GBar {
  unsigned cnt;        // barrier arrivals, monotonic
  unsigned gen;        // completed barrier rounds, monotonic
  unsigned done;       // phase-4 completions, monotonic
  unsigned pad[29];
};
__device__ GBar g_gb[16];

__device__ __forceinline__ void group_barrier(int b) {
  // snapshot BEFORE arrival (gen for this round can only advance after our add)
  unsigned snap = __hip_atomic_load(&g_gb[b].gen, __ATOMIC_RELAXED, __HIP_MEMORY_SCOPE_AGENT);
  if (threadIdx.x == 0) {
    unsigned old = __hip_atomic_fetch_add(&g_gb[b].cnt, 1u, __ATOMIC_ACQ_REL,
                                          __HIP_MEMORY_SCOPE_AGENT);
    if ((old & 15u) == 15u)
      __hip_atomic_store(&g_gb[b].gen, snap + 1u, __ATOMIC_RELEASE,
                         __HIP_MEMORY_SCOPE_AGENT);
  }
  // relaxed polls: read through to coherent point, NO invalidate per poll
  while (__hip_atomic_load(&g_gb[b].gen, __ATOMIC_RELAXED, __HIP_MEMORY_SCOPE_AGENT) == snap)
    __builtin_amdgcn_s_sleep(1);
  // single acquire: pairs with the release chain through cnt/gen
  (void)__hip_atomic_load(&g_gb[b].gen, __ATOMIC_ACQUIRE, __HIP_MEMORY_SCOPE_AGENT);
}

// ---------------- register/shuffle gate engine ----------------
template<int P>
__device__ __forceinline__ void ry_gate(float2 (&a)[16], float c, float s, int lane) {
  if constexpr (P < 4) {
    constexpr int m = 1 << P;
#pragma unroll
    for (int r0 = 0; r0 < 16; ++r0) {
      if (!(r0 & m)) {
        int r1 = r0 | m;
        float2 a0 = a[r0], a1 = a[r1];
        a[r0] = make_float2(c * a0.x - s * a1.x, c * a0.y - s * a1.y);
        a[r1] = make_float2(s * a0.x + c * a1.x, s * a0.y + c * a1.y);
      }
    }
  } else {
    constexpr int xm = 1 << (P - 4);
    bool up = (lane >> (P - 4)) & 1;
    float sg = up ? s : -s;
#pragma unroll
    for (int r = 0; r < 16; ++r) {
      float wx = __shfl_xor(a[r].x, xm, 64);
      float wy = __shfl_xor(a[r].y, xm, 64);
      a[r].x = c * a[r].x + sg * wx;
      a[r].y = c * a[r].y + sg * wy;
    }
  }
}

template<int P, int Q>
__device__ __forceinline__ void crx_gate(float2 (&a)[16], float c, float s, int lane) {
  if constexpr (P < 4) {
    constexpr int m = 1 << P;
#pragma unroll
    for (int r0 = 0; r0 < 16; ++r0) {
      if (!(r0 & m)) {
        int r1 = r0 | m;
        bool act;
        if constexpr (Q < 4) act = (r0 >> Q) & 1;
        else act = (lane >> (Q - 4)) & 1;
        if (act) {
          float2 a0 = a[r0], a1 = a[r1];
          a[r0] = make_float2(c * a0.x + s * a1.y, c * a0.y - s * a1.x);
          a[r1] = make_float2(c * a1.x + s * a0.y, c * a1.y - s * a0.x);
        }
      }
    }
  } else {
    constexpr int xm = 1 << (P - 4);
#pragma unroll
    for (int r = 0; r < 16; ++r) {
      float wx = __shfl_xor(a[r].x, xm, 64);
      float wy = __shfl_xor(a[r].y, xm, 64);
      bool act;
      if constexpr (Q < 4) act = (r >> Q) & 1;
      else act = (lane >> (Q - 4)) & 1;
      if (act) {
        float nx = c * a[r].x + s * wy;
        float ny = c * a[r].y - s * wx;
        a[r].x = nx; a[r].y = ny;
      }
    }
  }
}

template<bool ADJ, int G>
__device__ __forceinline__ void one_gate(float2 (&a)[16], const float2* sc, int lane) {
  constexpr Gate g = GTC.g[ADJ ? (39 - G) : G];
  float2 scv = sc[g.pidx];
  float s = ADJ ? -scv.x : scv.x;
  float c = scv.y;
  if constexpr (g.ry != 0) ry_gate<g.tbit>(a, c, s, lane);
  else crx_gate<g.tbit, g.cbit>(a, c, s, lane);
}

template<bool ADJ, int... I>
__device__ __forceinline__ void run_layer_impl(float2 (&a)[16], const float2* sc,
                                               int lane, std::integer_sequence<int, I...>) {
  (one_gate<ADJ, I>(a, sc, lane), ...);
}
template<bool ADJ>
__device__ __forceinline__ void run_layer(float2 (&a)[16], const float2* sc, int lane) {
  run_layer_impl<ADJ>(a, sc, lane, std::make_integer_sequence<int, 40>{});
}

// Mix using a single LDS-resident matrix row: a[r] = sum_ap Mrow[ap]*src[b][ap][lane*16+r]
__device__ __forceinline__ void mix_load_row(float2 (&a)[16], const float2* __restrict__ src,
                                             const float2* Mrow, int b, int lane) {
#pragma unroll
  for (int r = 0; r < 16; ++r) a[r] = make_float2(0.f, 0.f);
#pragma unroll
  for (int ap = 0; ap < 16; ++ap) {
    float2 m = Mrow[ap];
    const float4* col4 = (const float4*)(src + (size_t)(b * 16 + ap) * 1024) + lane * 8;
#pragma unroll
    for (int q = 0; q < 8; ++q) {
      float4 v = col4[q];
      a[2 * q].x     += m.x * v.x - m.y * v.y;
      a[2 * q].y     += m.x * v.y + m.y * v.x;
      a[2 * q + 1].x += m.x * v.z - m.y * v.w;
      a[2 * q + 1].y += m.x * v.w + m.y * v.z;
    }
  }
}

// Old-style mix (full matrix in global) for the fallback path.
__device__ __forceinline__ void mix_load(float2 (&a)[16], const float2* __restrict__ src,
                                         const float2* __restrict__ M, int b, int aa, int lane) {
#pragma unroll
  for (int r = 0; r < 16; ++r) a[r] = make_float2(0.f, 0.f);
#pragma unroll
  for (int ap = 0; ap < 16; ++ap) {
    float2 m = M[aa * 16 + ap];
    const float4* col4 = (const float4*)(src + (size_t)(b * 16 + ap) * 1024) + lane * 8;
#pragma unroll
    for (int q = 0; q < 8; ++q) {
      float4 v = col4[q];
      a[2 * q].x     += m.x * v.x - m.y * v.y;
      a[2 * q].y     += m.x * v.y + m.y * v.x;
      a[2 * q + 1].x += m.x * v.z - m.y * v.w;
      a[2 * q + 1].y += m.x * v.w + m.y * v.z;
    }
  }
}

__device__ __forceinline__ void store_col(float2* dst, int blk, int lane, float2 (&a)[16]) {
  float4* o4 = (float4*)(dst + (size_t)blk * 1024) + lane * 8;
#pragma unroll
  for (int q = 0; q < 8; ++q)
    o4[q] = make_float4(a[2 * q].x, a[2 * q].y, a[2 * q + 1].x, a[2 * q + 1].y);
}

// ---------------- the fused kernel (normal launch + group barriers) ----------------
__global__ __launch_bounds__(64) void k_fused(const float* __restrict__ x,
                                              const float* __restrict__ W_fp,
                                              const float* __restrict__ b_fp,
                                              const float* __restrict__ prep,
                                              const float* __restrict__ sig,
                                              const float* __restrict__ qff,
                                              const float* __restrict__ W_out,
                                              const float* __restrict__ b_out,
                                              float* __restrict__ out,
                                              float2* __restrict__ state0,
                                              float2* __restrict__ state1,
                                              float* __restrict__ sv) {
  int blk = blockIdx.x, lane = threadIdx.x;     // blk = b*16 + a
  int b = blk >> 4, aa = blk & 15;

  __shared__ float h[64];
  __shared__ float2 U[256];                     // prepare unitary U[a*16 + j]
  __shared__ float2 scs[80];                    // ts (sin,cos) for this column (t = aa)
  __shared__ float2 qscs[40];                   // qff (sin,cos)
  __shared__ float2 m1row[16], m2row[16], mendrow[16];

  // sv zeroing for this b (ordered before phase-4 adds via barrier chain)
  if (aa == 0 && lane < 30) sv[b * 30 + lane] = 0.f;

  // ---- phase 0a: ts params for (b, t = aa) ----
  {
    int t = aa;
    int f = lane, k = f >> 1;
    float div = expf(-(float)(2 * k) * (logf(10000.f) / 64.f));
    float ang = (float)t * div;
    float pe = (f & 1) ? cosf(ang) : sinf(ang);
    h[f] = x[(b * 64 + f) * 16 + t] + pe;
    __syncthreads();
    for (int j = lane; j < 80; j += 64) {
      float acc = b_fp[j];
      const float* wr = W_fp + j * 64;
#pragma unroll 8
      for (int ff = 0; ff < 64; ++ff) acc += h[ff] * wr[ff];
      float sg = 1.f / (1.f + expf(-acc));
      float s, c;
      sincosf(sg * 3.14159265358979323846f, &s, &c);   // theta/2 = sigmoid*pi
      scs[j] = make_float2(s, c);
    }
  }

  // ---- phase 0b: build the 16x16 prepare unitary U (replicated per block) ----
  for (int it = lane; it < 256; it += 64)
    U[it] = make_float2((it >> 4) == (it & 15) ? 1.f : 0.f, 0.f);
  __syncthreads();
  for (int ly = 0; ly < 4; ++ly) {
    for (int qi = 0; qi < 4; ++qi) {
      int p = 3 - qi;
      float s, c;
      sincosf(0.5f * prep[ly * 8 + qi * 2 + 0], &s, &c);
      for (int it = lane; it < 128; it += 64) {
        int j = it & 15, pp = it >> 4;
        int a0 = insert_zero(pp, p), a1 = a0 | (1 << p);
        float2 u0 = U[a0 * 16 + j], u1 = U[a1 * 16 + j];
        U[a0 * 16 + j] = make_float2(c * u0.x - s * u1.x, c * u0.y - s * u1.y);
        U[a1 * 16 + j] = make_float2(s * u0.x + c * u1.x, s * u0.y + c * u1.y);
      }
      __syncthreads();
      sincosf(0.5f * prep[ly * 8 + qi * 2 + 1], &s, &c);
      for (int it = lane; it < 128; it += 64) {
        int j = it & 15, pp = it >> 4;
        int a0 = insert_zero(pp, p), a1 = a0 | (1 << p);
        float2 u0 = U[a0 * 16 + j], u1 = U[a1 * 16 + j];
        U[a0 * 16 + j] = make_float2(c * u0.x + s * u0.y, c * u0.y - s * u0.x);
        U[a1 * 16 + j] = make_float2(c * u1.x - s * u1.y, c * u1.y + s * u1.x);
      }
      __syncthreads();
    }
    for (int i = 0; i < 3; ++i) {
      int pc = 3 - i, pt = 2 - i;
      {
        int j = lane & 15, pp = lane >> 4;     // exactly 64 items
        int m = insert_zero(pp, pt);
        m = insert_zero(m, pc);
        int a0 = m | (1 << pc), a1 = a0 | (1 << pt);
        float2 t0 = U[a0 * 16 + j], t1 = U[a1 * 16 + j];
        U[a0 * 16 + j] = t1;
        U[a1 * 16 + j] = t0;
      }
      __syncthreads();
    }
  }

  // ---- phase 0c: per-block matrix rows + qsc + init scalar ----
  float2 e0, e1, e2, e3;
  sincosf(sig[0], &e0.y, &e0.x);
  sincosf(sig[1], &e1.y, &e1.x);
  sincosf(sig[2], &e2.y, &e2.x);
  sincosf(sig[3], &e3.y, &e3.x);
  if (lane < 16) {
    float2 acc1 = make_float2(0.f, 0.f), acc2 = make_float2(0.f, 0.f);
    for (int cix = 0; cix < 16; ++cix) {
      float2 t = cmul(U[aa * 16 + cix], conj2(U[lane * 16 + cix]));
      acc1 = cfma(t, (cix == 0) ? e1 : conj2(e1), acc1);
      acc2 = cfma(t, (cix == 0) ? e2 : conj2(e2), acc2);
    }
    m1row[lane] = acc1;                         // (U D1 U^dag)[aa][lane]
    m2row[lane] = acc2;                         // (U D2 U^dag)[aa][lane]
    float2 v3 = (aa == 0) ? e3 : conj2(e3);
    mendrow[lane] = cmul(v3, conj2(U[lane * 16 + aa]));   // (D3 U^dag)[aa][lane]
  }
  if (lane < 40) {
    float s, c;
    sincosf(0.5f * qff[lane], &s, &c);
    qscs[lane] = make_float2(s, c);
  }
  float2 m0 = cmul(U[aa * 16 + 0], e0);         // (U D0)[aa][0] * e^{i sig0}
  __syncthreads();

  const float2* sc = scs;
  float2 a[16];

  // ---- phase 1: init |0..0> column + select fwd ----
#pragma unroll
  for (int r = 0; r < 16; ++r) a[r] = make_float2(0.f, 0.f);
  if (lane == 0) a[0] = m0;
  run_layer<false>(a, sc, lane);
  run_layer<false>(a, sc + 40, lane);
  store_col(state0, blk, lane, a);
  group_barrier(b);

  // ---- phase 2: mix M1 + select adjoint ----
  mix_load_row(a, state0, m1row, b, lane);
  run_layer<true>(a, sc + 40, lane);
  run_layer<true>(a, sc, lane);
  store_col(state1, blk, lane, a);
  group_barrier(b);

  // ---- phase 3: mix M2 + select fwd ----
  mix_load_row(a, state1, m2row, b, lane);
  run_layer<false>(a, sc, lane);
  run_layer<false>(a, sc + 40, lane);
  store_col(state0, blk, lane, a);
  group_barrier(b);

  // ---- phase 4: mix Mend + qff + expvals partials ----
  mix_load_row(a, state0, mendrow, b, lane);
  run_layer<false>(a, qscs, lane);
  {
    float obs[30];
#pragma unroll
    for (int p = 0; p <= 9; ++p) {
      int i = 9 - p;
      float cr = 0.f, ci = 0.f, zz = 0.f;
      if (p < 4) {
        int m = 1 << p;
#pragma unroll
        for (int r0 = 0; r0 < 16; ++r0) {
          if (!(r0 & m)) {
            float2 A0 = a[r0], A1 = a[r0 | m];
            cr += A0.x * A1.x + A0.y * A1.y;
            ci += A0.x * A1.y - A0.y * A1.x;
            zz += (A0.x * A0.x + A0.y * A0.y) - (A1.x * A1.x + A1.y * A1.y);
          }
        }
      } else {
        int xm = 1 << (p - 4);
        bool up = (lane >> (p - 4)) & 1;
#pragma unroll
        for (int r = 0; r < 16; ++r) {
          float wx = __shfl_xor(a[r].x, xm, 64);
          float wy = __shfl_xor(a[r].y, xm, 64);
          float n2 = a[r].x * a[r].x + a[r].y * a[r].y;
          if (!up) {
            cr += a[r].x * wx + a[r].y * wy;
            ci += a[r].x * wy - a[r].y * wx;
            zz += n2;
          } else {
            zz -= n2;
          }
        }
      }
      obs[i] = 2.f * cr;
      obs[10 + i] = 2.f * ci;
      obs[20 + i] = zz;
    }
#pragma unroll
    for (int j = 0; j < 30; ++j) {
      float v = obs[j];
      for (int off = 32; off; off >>= 1) v += __shfl_down(v, off, 64);
      if (lane == 0) atomicAdd(&sv[b * 30 + j], v);
    }
  }

  // ---- phase 5: last-arriving block of group b computes its output row ----
  int lastflag = 0;
  if (lane == 0) {
    unsigned old = __hip_atomic_fetch_add(&g_gb[b].done, 1u, __ATOMIC_ACQ_REL,
                                          __HIP_MEMORY_SCOPE_AGENT);
    lastflag = ((old & 15u) == 15u) ? 1 : 0;
  }
  lastflag = __shfl(lastflag, 0, 64);
  if (lastflag) {
    (void)__hip_atomic_load(&g_gb[b].done, __ATOMIC_ACQUIRE, __HIP_MEMORY_SCOPE_AGENT);
    if (lane < 8) {
      float acc = b_out[lane];
#pragma unroll
      for (int j = 0; j < 30; ++j) acc += W_out[lane * 30 + j] * sv[b * 30 + j];
      out[b * 8 + lane] = acc;
    }
  }
}

// ================= fallback multi-kernel path (ws too small) =================

__global__ __launch_bounds__(128) void k_ts(const float* __restrict__ x,
                                            const float* __restrict__ W,
                                            const float* __restrict__ bias,
                                            float2* __restrict__ tsc) {
  int blk = blockIdx.x;
  int b = blk >> 4, t = blk & 15;
  __shared__ float h[64];
  int tid = threadIdx.x;
  if (tid < 64) {
    int f = tid, k = f >> 1;
    float div = expf(-(float)(2 * k) * (logf(10000.f) / 64.f));
    float ang = (float)t * div;
    float pe = (f & 1) ? cosf(ang) : sinf(ang);
    h[f] = x[(b * 64 + f) * 16 + t] + pe;
  }
  __syncthreads();
  if (tid < 80) {
    float acc = bias[tid];
    const float* wr = W + tid * 64;
#pragma unroll 8
    for (int f = 0; f < 64; ++f) acc += h[f] * wr[f];
    float sg = 1.f / (1.f + expf(-acc));
    float s, c;
    sincosf(sg * 3.14159265358979323846f, &s, &c);
    tsc[blk * 80 + tid] = make_float2(s, c);
  }
}

__global__ __launch_bounds__(256) void k_build(const float* __restrict__ prep,
                                               const float* __restrict__ sig,
                                               const float* __restrict__ qffp,
                                               float2* __restrict__ mats,
                                               float2* __restrict__ qsc) {
  __shared__ float2 U[256];
  int tid = threadIdx.x;
  if (tid < 40) {
    float s, c;
    sincosf(0.5f * qffp[tid], &s, &c);
    qsc[tid] = make_float2(s, c);
  }
  U[tid] = make_float2((tid >> 4) == (tid & 15) ? 1.f : 0.f, 0.f);
  __syncthreads();
  for (int ly = 0; ly < 4; ++ly) {
    for (int qi = 0; qi < 4; ++qi) {
      int p = 3 - qi;
      float th = prep[ly * 8 + qi * 2 + 0];
      float s, c;
      sincosf(0.5f * th, &s, &c);
      if (tid < 128) {
        int j = tid & 15, pp = tid >> 4;
        int a0 = insert_zero(pp, p), a1 = a0 | (1 << p);
        float2 u0 = U[a0 * 16 + j], u1 = U[a1 * 16 + j];
        U[a0 * 16 + j] = make_float2(c * u0.x - s * u1.x, c * u0.y - s * u1.y);
        U[a1 * 16 + j] = make_float2(s * u0.x + c * u1.x, s * u0.y + c * u1.y);
      }
      __syncthreads();
      th = prep[ly * 8 + qi * 2 + 1];
      sincosf(0.5f * th, &s, &c);
      if (tid < 128) {
        int j = tid & 15, pp = tid >> 4;
        int a0 = insert_zero(pp, p), a1 = a0 | (1 << p);
        float2 u0 = U[a0 * 16 + j], u1 = U[a1 * 16 + j];
        U[a0 * 16 + j] = make_float2(c * u0.x + s * u0.y, c * u0.y - s * u0.x);
        U[a1 * 16 + j] = make_float2(c * u1.x - s * u1.y, c * u1.y + s * u1.x);
      }
      __syncthreads();
    }
    for (int i = 0; i < 3; ++i) {
      int pc = 3 - i, pt = 2 - i;
      if (tid < 64) {
        int j = tid & 15, pp = tid >> 4;
        int m = insert_zero(pp, pt);
        m = insert_zero(m, pc);
        int a0 = m | (1 << pc), a1 = a0 | (1 << pt);
        float2 t0 = U[a0 * 16 + j], t1 = U[a1 * 16 + j];
        U[a0 * 16 + j] = t1;
        U[a1 * 16 + j] = t0;
      }
      __syncthreads();
    }
  }
  int a = tid >> 4, bb = tid & 15;
  float2 e1, e2, e3;
  sincosf(sig[1], &e1.y, &e1.x);
  sincosf(sig[2], &e2.y, &e2.x);
  sincosf(sig[3], &e3.y, &e3.x);
  float2 acc1 = make_float2(0.f, 0.f), acc2 = make_float2(0.f, 0.f);
  for (int cix = 0; cix < 16; ++cix) {
    float2 t = cmul(U[a * 16 + cix], conj2(U[bb * 16 + cix]));
    acc1 = cfma(t, (cix == 0) ? e1 : conj2(e1), acc1);
    acc2 = cfma(t, (cix == 0) ? e2 : conj2(e2), acc2);
  }
  mats[16 + tid] = acc1;
  mats[272 + tid] = acc2;
  float2 v3 = (a == 0) ? e3 : conj2(e3);
  mats[528 + tid] = cmul(v3, conj2(U[bb * 16 + a]));
  if (tid < 16) {
    float2 e0;
    sincosf(sig[0], &e0.y, &e0.x);
    mats[tid] = cmul(U[tid * 16 + 0], e0);
  }
}

template<bool ADJ, int MODE>
__global__ __launch_bounds__(64) void k_sel(const float2* __restrict__ src,
                                            float2* __restrict__ dst,
                                            const float2* __restrict__ sc_ts,
                                            const float2* __restrict__ mat) {
  int blk = blockIdx.x, lane = threadIdx.x;
  const float2* __restrict__ sc = sc_ts + blk * 80;
  float2 a[16];
  if constexpr (MODE == 0) {
#pragma unroll
    for (int r = 0; r < 16; ++r) a[r] = make_float2(0.f, 0.f);
    if (lane == 0) a[0] = mat[blk & 15];
  } else if constexpr (MODE == 1) {
    const float4* g4 = (const float4*)(src + (size_t)blk * 1024) + lane * 8;
#pragma unroll
    for (int q = 0; q < 8; ++q) {
      float4 v = g4[q];
      a[2 * q]     = make_float2(v.x, v.y);
      a[2 * q + 1] = make_float2(v.z, v.w);
    }
  } else {
    mix_load(a, src, mat, blk >> 4, blk & 15, lane);
  }
  if constexpr (ADJ) {
    run_layer<true>(a, sc + 40, lane);
    run_layer<true>(a, sc, lane);
  } else {
    run_layer<false>(a, sc, lane);
    run_layer<false>(a, sc + 40, lane);
  }
  store_col(dst, blk, lane, a);
}

__global__ __launch_bounds__(64) void k_qff_exp(const float2* __restrict__ src,
                                                const float2* __restrict__ mend,
                                                const float2* __restrict__ qsc,
                                                float* __restrict__ sv) {
  int blk = blockIdx.x, lane = threadIdx.x;
  int b = blk >> 4, aa = blk & 15;
  float2 a[16];
  mix_load(a, src, mend, b, aa, lane);
  run_layer<false>(a, qsc, lane);
  float obs[30];
#pragma unroll
  for (int p = 0; p <= 9; ++p) {
    int i = 9 - p;
    float cr = 0.f, ci = 0.f, zz = 0.f;
    if (p < 4) {
      int m = 1 << p;
#pragma unroll
      for (int r0 = 0; r0 < 16; ++r0) {
        if (!(r0 & m)) {
          float2 A0 = a[r0], A1 = a[r0 | m];
          cr += A0.x * A1.x + A0.y * A1.y;
          ci += A0.x * A1.y - A0.y * A1.x;
          zz += (A0.x * A0.x + A0.y * A0.y) - (A1.x * A1.x + A1.y * A1.y);
        }
      }
    } else {
      int xm = 1 << (p - 4);
      bool up = (lane >> (p - 4)) & 1;
#pragma unroll
      for (int r = 0; r < 16; ++r) {
        float wx = __shfl_xor(a[r].x, xm, 64);
        float wy = __shfl_xor(a[r].y, xm, 64);
        float n2 = a[r].x * a[r].x + a[r].y * a[r].y;
        if (!up) {
          cr += a[r].x * wx + a[r].y * wy;
          ci += a[r].x * wy - a[r].y * wx;
          zz += n2;
        } else {
          zz -= n2;
        }
      }
    }
    obs[i] = 2.f * cr;
    obs[10 + i] = 2.f * ci;
    obs[20 + i] = zz;
  }
#pragma unroll
  for (int j = 0; j < 30; ++j) {
    float v = obs[j];
    for (int off = 32; off; off >>= 1) v += __shfl_down(v, off, 64);
    if (lane == 0) atomicAdd(&sv[b * 30 + j], v);
  }
}

__global__ __launch_bounds__(128) void k_out(const float* __restrict__ sv,
                                             const float* __restrict__ W,
                                             const float* __restrict__ bo,
                                             float* __restrict__ out) {
  int tid = threadIdx.x;
  int b = tid >> 3, o = tid & 7;
  float acc = bo[o];
#pragma unroll
  for (int j = 0; j < 30; ++j) acc += W[o * 30 + j] * sv[b * 30 + j];
  out[tid] = acc;
}

__global__ __launch_bounds__(256) void k_anc(float2* __restrict__ state,
                                             const float2* __restrict__ M) {
  __shared__ float2 sM[256];
  int tid = threadIdx.x;
  sM[tid] = M[tid];
  __syncthreads();
  int t = blockIdx.x * 256 + tid;
  int b = t >> 10, n = t & 1023;
  float2* p = state + b * 16384 + n;
  float2 v[16];
#pragma unroll
  for (int ap = 0; ap < 16; ++ap) v[ap] = p[ap << 10];
#pragma unroll
  for (int ao = 0; ao < 16; ++ao) {
    float re = 0.f, im = 0.f;
#pragma unroll
    for (int ap = 0; ap < 16; ++ap) {
      float2 m = sM[ao * 16 + ap];
      re += m.x * v[ap].x - m.y * v[ap].y;
      im += m.x * v[ap].y + m.y * v[ap].x;
    }
    p[ao << 10] = make_float2(re, im);
  }
}

extern "C" void kernel_launch(void* const* d_in, const int* in_sizes, int n_in,
                              void* d_out, int out_size, void* d_ws, size_t ws_size,
                              hipStream_t stream) {
  const float* x     = (const float*)d_in[0];
  const float* W_fp  = (const float*)d_in[1];
  const float* b_fp  = (const float*)d_in[2];
  const float* prep  = (const float*)d_in[3];
  const float* sig   = (const float*)d_in[4];
  const float* qff   = (const float*)d_in[5];
  const float* W_out = (const float*)d_in[6];
  const float* b_out = (const float*)d_in[7];
  float* out = (float*)d_out;

  char* ws = (char*)d_ws;
  const size_t SZ_STATE = 2097152;      // 256 cols * 1024 * 8 B
  const size_t SZ_SV    = 1920;         // 16*30 float

  if (ws_size >= 2 * SZ_STATE + SZ_SV) {
    // fused single-dispatch path (normal launch; per-b group barriers inside)
    float2* state0 = (float2*)ws;
    float2* state1 = (float2*)(ws + SZ_STATE);
    float*  sv     = (float*)(ws + 2 * SZ_STATE);
    k_fused<<<dim3(256), dim3(64), 0, stream>>>(x, W_fp, b_fp, prep, sig, qff,
                                                W_out, b_out, out, state0, state1, sv);
    return;
  }

  // fallback multi-kernel path (original structure)
  const size_t SZ_TSC   = 163840;
  const size_t SZ_MATS  = 6272;
  const size_t SZ_QSC   = 320;
  bool pp = ws_size >= 2 * SZ_STATE + SZ_TSC + SZ_MATS + SZ_QSC + SZ_SV;

  float2* state0 = (float2*)ws;
  float2* state1 = pp ? (float2*)(ws + SZ_STATE) : nullptr;
  char* tail = ws + (pp ? 2 * SZ_STATE : SZ_STATE);
  float2* tsc  = (float2*)tail;
  float2* mats = (float2*)(tail + SZ_TSC);
  float2* qsc  = (float2*)(tail + SZ_TSC + SZ_MATS);
  float*  sv   = (float*) (tail + SZ_TSC + SZ_MATS + SZ_QSC);

  hipMemsetAsync(sv, 0, SZ_SV, stream);
  k_ts<<<256, 128, 0, stream>>>(x, W_fp, b_fp, tsc);
  k_build<<<1, 256, 0, stream>>>(prep, sig, qff, mats, qsc);

  if (pp) {
    k_sel<false, 0><<<256, 64, 0, stream>>>(nullptr, state0, tsc, mats);
    k_sel<true,  2><<<256, 64, 0, stream>>>(state0, state1, tsc, mats + 16);
    k_sel<false, 2><<<256, 64, 0, stream>>>(state1, state0, tsc, mats + 272);
  } else {
    k_sel<false, 0><<<256, 64, 0, stream>>>(nullptr, state0, tsc, mats);
    k_anc<<<64, 256, 0, stream>>>(state0, mats + 16);
    k_sel<true,  1><<<256, 64, 0, stream>>>(state0, state0, tsc, nullptr);
    k_anc<<<64, 256, 0, stream>>>(state0, mats + 272);
    k_sel<false, 1><<<256, 64, 0, stream>>>(state0, state0, tsc, nullptr);
  }
  k_qff_exp<<<256, 64, 0, stream>>>(state0, mats + 528, qsc, sv);
  k_out<<<1, 128, 0, stream>>>(sv, W_out, b_out, out);
}

// Round 4
// 214.629 us; speedup vs baseline: 1.4805x; 1.0865x over previous
//
#include <hip/hip_runtime.h>
#include <math.h>
#include <utility>

// B=16, T=16, FDIM=64, ODIM=8, NQ=10, NA=4, LAYERS=2, DEGREE=3.
// State: float2 state[b][a][n], n<1024 (qubit i <-> bit 9-i of n), a<16
// (ancilla qubit NQ+qi <-> bit 3-qi of a).
// Wave-resident select: one 64-lane wave owns one (b,a) column.
// Amp mapping: n = lane*16 + r  (bits [3:0]=r in-thread, [9:4]=lane).
// Gates on bit<4: thread-local. Gates on bit>=4: cross-lane butterfly.
//   xor1/xor2 -> DPP quad_perm, xor8 -> DPP row_ror:8 (VALU-latency)
//   xor4/16/32 -> __shfl_xor (DS)
// Per-run_layer sin/cos table preloaded into registers (constexpr-indexed).
//
// FUSED, SINGLE NORMAL DISPATCH: 256 blocks x 64 lanes (one wave each).
// Cross-block sync is per-b groups of 16 blocks (monotonic cnt/gen words,
// relaxed polls + single acquire) -- structure identical to the round-3
// version that passed.

struct Gate { int ry; int tbit; int cbit; int pidx; };
struct GateTab { Gate g[40]; };

constexpr GateTab make_gates1() {
  GateTab tb{};
  int pos = 0, idx = 0;
  for (int i = 0; i < 10; ++i) { tb.g[pos] = Gate{1, 9 - i, -1, idx}; ++pos; ++idx; }
  for (int i = 9; i >= 0; --i) { tb.g[pos] = Gate{0, 9 - ((i + 1) % 10), 9 - i, idx}; ++pos; ++idx; }
  for (int i = 0; i < 10; ++i) { tb.g[pos] = Gate{1, 9 - i, -1, idx}; ++pos; ++idx; }
  for (int k = 0; k < 10; ++k) {
    int i = (k == 0) ? 9 : (k - 1);
    tb.g[pos] = Gate{0, 9 - ((i + 9) % 10), 9 - i, idx}; ++pos; ++idx;
  }
  return tb;
}
constexpr GateTab GTC = make_gates1();

__device__ __forceinline__ int insert_zero(int v, int p) {
  return ((v >> p) << (p + 1)) | (v & ((1 << p) - 1));
}
__device__ __forceinline__ float2 cmul(float2 A, float2 B) {
  return make_float2(A.x * B.x - A.y * B.y, A.x * B.y + A.y * B.x);
}
__device__ __forceinline__ float2 conj2(float2 A) { return make_float2(A.x, -A.y); }
__device__ __forceinline__ float2 cfma(float2 A, float2 B, float2 acc) {
  acc.x += A.x * B.x - A.y * B.y;
  acc.y += A.x * B.y + A.y * B.x;
  return acc;
}

// ---------------- cross-lane xor: DPP where possible ----------------
// quad_perm [1,0,3,2] = 0xB1 (xor1), [2,3,0,1] = 0x4E (xor2),
// row_ror:8 = 0x128 (xor8 within each 16-lane row since (l+8)%16 == l^8).
template<int XM>
__device__ __forceinline__ float lxor(float v) {
  if constexpr (XM == 1) {
    int r = __builtin_amdgcn_update_dpp(__float_as_int(v), __float_as_int(v),
                                        0xB1, 0xF, 0xF, true);
    return __int_as_float(r);
  } else if constexpr (XM == 2) {
    int r = __builtin_amdgcn_update_dpp(__float_as_int(v), __float_as_int(v),
                                        0x4E, 0xF, 0xF, true);
    return __int_as_float(r);
  } else if constexpr (XM == 8) {
    int r = __builtin_amdgcn_update_dpp(__float_as_int(v), __float_as_int(v),
                                        0x128, 0xF, 0xF, true);
    return __int_as_float(r);
  } else {
    return __shfl_xor(v, XM, 64);
  }
}

// ---------------- per-b group barrier (16 participants) ----------------
// Monotonic words; zero-initialized at module load; never reset (mod-16
// round detection), so graph replay / multiple launches are safe.
struct alignas(128) GBar {
  unsigned cnt;        // barrier arrivals, monotonic
  unsigned gen;        // completed barrier rounds, monotonic
  unsigned done;       // phase-4 completions, monotonic
  unsigned pad[29];
};
__device__ GBar g_gb[16];

__device__ __forceinline__ void group_barrier(int b) {
  unsigned snap = __hip_atomic_load(&g_gb[b].gen, __ATOMIC_RELAXED, __HIP_MEMORY_SCOPE_AGENT);
  if (threadIdx.x == 0) {
    unsigned old = __hip_atomic_fetch_add(&g_gb[b].cnt, 1u, __ATOMIC_ACQ_REL,
                                          __HIP_MEMORY_SCOPE_AGENT);
    if ((old & 15u) == 15u)
      __hip_atomic_store(&g_gb[b].gen, snap + 1u, __ATOMIC_RELEASE,
                         __HIP_MEMORY_SCOPE_AGENT);
  }
  while (__hip_atomic_load(&g_gb[b].gen, __ATOMIC_RELAXED, __HIP_MEMORY_SCOPE_AGENT) == snap)
    __builtin_amdgcn_s_sleep(1);
  (void)__hip_atomic_load(&g_gb[b].gen, __ATOMIC_ACQUIRE, __HIP_MEMORY_SCOPE_AGENT);
}

// ---------------- register/shuffle gate engine ----------------
template<int P>
__device__ __forceinline__ void ry_gate(float2 (&a)[16], float c, float s, int lane) {
  if constexpr (P < 4) {
    constexpr int m = 1 << P;
#pragma unroll
    for (int r0 = 0; r0 < 16; ++r0) {
      if (!(r0 & m)) {
        int r1 = r0 | m;
        float2 a0 = a[r0], a1 = a[r1];
        a[r0] = make_float2(c * a0.x - s * a1.x, c * a0.y - s * a1.y);
        a[r1] = make_float2(s * a0.x + c * a1.x, s * a0.y + c * a1.y);
      }
    }
  } else {
    constexpr int xm = 1 << (P - 4);
    bool up = (lane >> (P - 4)) & 1;
    float sg = up ? s : -s;
#pragma unroll
    for (int r = 0; r < 16; ++r) {
      float wx = lxor<xm>(a[r].x);
      float wy = lxor<xm>(a[r].y);
      a[r].x = c * a[r].x + sg * wx;
      a[r].y = c * a[r].y + sg * wy;
    }
  }
}

template<int P, int Q>
__device__ __forceinline__ void crx_gate(float2 (&a)[16], float c, float s, int lane) {
  if constexpr (P < 4) {
    constexpr int m = 1 << P;
#pragma unroll
    for (int r0 = 0; r0 < 16; ++r0) {
      if (!(r0 & m)) {
        int r1 = r0 | m;
        bool act;
        if constexpr (Q < 4) act = (r0 >> Q) & 1;
        else act = (lane >> (Q - 4)) & 1;
        if (act) {
          float2 a0 = a[r0], a1 = a[r1];
          a[r0] = make_float2(c * a0.x + s * a1.y, c * a0.y - s * a1.x);
          a[r1] = make_float2(c * a1.x + s * a0.y, c * a1.y - s * a0.x);
        }
      }
    }
  } else {
    constexpr int xm = 1 << (P - 4);
#pragma unroll
    for (int r = 0; r < 16; ++r) {
      float wx = lxor<xm>(a[r].x);
      float wy = lxor<xm>(a[r].y);
      bool act;
      if constexpr (Q < 4) act = (r >> Q) & 1;
      else act = (lane >> (Q - 4)) & 1;
      if (act) {
        float nx = c * a[r].x + s * wy;
        float ny = c * a[r].y - s * wx;
        a[r].x = nx; a[r].y = ny;
      }
    }
  }
}

template<bool ADJ, int G>
__device__ __forceinline__ void one_gate(float2 (&a)[16], const float2 (&sc)[40], int lane) {
  constexpr Gate g = GTC.g[ADJ ? (39 - G) : G];
  float2 scv = sc[g.pidx];          // constexpr index -> stays in VGPRs
  float s = ADJ ? -scv.x : scv.x;
  float c = scv.y;
  if constexpr (g.ry != 0) ry_gate<g.tbit>(a, c, s, lane);
  else crx_gate<g.tbit, g.cbit>(a, c, s, lane);
}

template<bool ADJ, int... I>
__device__ __forceinline__ void run_layer_impl(float2 (&a)[16], const float2 (&sc)[40],
                                               int lane, std::integer_sequence<int, I...>) {
  (one_gate<ADJ, I>(a, sc, lane), ...);
}

// Preload the 40-entry (sin,cos) table into registers, then run the 40 gates.
template<bool ADJ>
__device__ __forceinline__ void run_layer(float2 (&a)[16], const float2* sc, int lane) {
  float2 rsc[40];
#pragma unroll
  for (int i = 0; i < 40; ++i) rsc[i] = sc[i];
  run_layer_impl<ADJ>(a, rsc, lane, std::make_integer_sequence<int, 40>{});
}

// Mix using a single LDS-resident matrix row: a[r] = sum_ap Mrow[ap]*src[b][ap][lane*16+r]
__device__ __forceinline__ void mix_load_row(float2 (&a)[16], const float2* __restrict__ src,
                                             const float2* Mrow, int b, int lane) {
#pragma unroll
  for (int r = 0; r < 16; ++r) a[r] = make_float2(0.f, 0.f);
#pragma unroll
  for (int ap = 0; ap < 16; ++ap) {
    float2 m = Mrow[ap];
    const float4* col4 = (const float4*)(src + (size_t)(b * 16 + ap) * 1024) + lane * 8;
#pragma unroll
    for (int q = 0; q < 8; ++q) {
      float4 v = col4[q];
      a[2 * q].x     += m.x * v.x - m.y * v.y;
      a[2 * q].y     += m.x * v.y + m.y * v.x;
      a[2 * q + 1].x += m.x * v.z - m.y * v.w;
      a[2 * q + 1].y += m.x * v.w + m.y * v.z;
    }
  }
}

// Old-style mix (full matrix in global) for the fallback path.
__device__ __forceinline__ void mix_load(float2 (&a)[16], const float2* __restrict__ src,
                                         const float2* __restrict__ M, int b, int aa, int lane) {
#pragma unroll
  for (int r = 0; r < 16; ++r) a[r] = make_float2(0.f, 0.f);
#pragma unroll
  for (int ap = 0; ap < 16; ++ap) {
    float2 m = M[aa * 16 + ap];
    const float4* col4 = (const float4*)(src + (size_t)(b * 16 + ap) * 1024) + lane * 8;
#pragma unroll
    for (int q = 0; q < 8; ++q) {
      float4 v = col4[q];
      a[2 * q].x     += m.x * v.x - m.y * v.y;
      a[2 * q].y     += m.x * v.y + m.y * v.x;
      a[2 * q + 1].x += m.x * v.z - m.y * v.w;
      a[2 * q + 1].y += m.x * v.w + m.y * v.z;
    }
  }
}

__device__ __forceinline__ void store_col(float2* dst, int blk, int lane, float2 (&a)[16]) {
  float4* o4 = (float4*)(dst + (size_t)blk * 1024) + lane * 8;
#pragma unroll
  for (int q = 0; q < 8; ++q)
    o4[q] = make_float4(a[2 * q].x, a[2 * q].y, a[2 * q + 1].x, a[2 * q + 1].y);
}

// ---------------- the fused kernel (normal launch + group barriers) ----------------
__global__ __launch_bounds__(64, 1) void k_fused(const float* __restrict__ x,
                                                 const float* __restrict__ W_fp,
                                                 const float* __restrict__ b_fp,
                                                 const float* __restrict__ prep,
                                                 const float* __restrict__ sig,
                                                 const float* __restrict__ qff,
                                                 const float* __restrict__ W_out,
                                                 const float* __restrict__ b_out,
                                                 float* __restrict__ out,
                                                 float2* __restrict__ state0,
                                                 float2* __restrict__ state1,
                                                 float* __restrict__ sv) {
  int blk = blockIdx.x, lane = threadIdx.x;     // blk = b*16 + a
  int b = blk >> 4, aa = blk & 15;

  __shared__ __align__(16) float h[64];
  __shared__ float2 U[256];                     // prepare unitary U[a*16 + j]
  __shared__ float2 scs[80];                    // ts (sin,cos) for this column (t = aa)
  __shared__ float2 qscs[40];                   // qff (sin,cos)
  __shared__ float2 m1row[16], m2row[16], mendrow[16];

  // sv zeroing for this b (ordered before phase-4 adds via barrier chain)
  if (aa == 0 && lane < 30) sv[b * 30 + lane] = 0.f;

  // ---- phase 0a: ts params for (b, t = aa) ----
  {
    int t = aa;
    int f = lane, k = f >> 1;
    float div = expf(-(float)(2 * k) * (logf(10000.f) / 64.f));
    float ang = (float)t * div;
    float pe = (f & 1) ? cosf(ang) : sinf(ang);
    h[f] = x[(b * 64 + f) * 16 + t] + pe;
    __syncthreads();
    const float4* h4 = (const float4*)h;
    for (int j = lane; j < 80; j += 64) {
      float acc = b_fp[j];
      const float4* w4 = (const float4*)(W_fp + j * 64);
#pragma unroll
      for (int k4 = 0; k4 < 16; ++k4) {
        float4 hh = h4[k4], ww = w4[k4];
        acc += hh.x * ww.x + hh.y * ww.y + hh.z * ww.z + hh.w * ww.w;
      }
      float sg = 1.f / (1.f + expf(-acc));
      float s, c;
      sincosf(sg * 3.14159265358979323846f, &s, &c);   // theta/2 = sigmoid*pi
      scs[j] = make_float2(s, c);
    }
  }

  // ---- phase 0b: build the 16x16 prepare unitary U (replicated per block) ----
  for (int it = lane; it < 256; it += 64)
    U[it] = make_float2((it >> 4) == (it & 15) ? 1.f : 0.f, 0.f);
  __syncthreads();
  for (int ly = 0; ly < 4; ++ly) {
    for (int qi = 0; qi < 4; ++qi) {
      int p = 3 - qi;
      float s, c;
      sincosf(0.5f * prep[ly * 8 + qi * 2 + 0], &s, &c);
      for (int it = lane; it < 128; it += 64) {
        int j = it & 15, pp = it >> 4;
        int a0 = insert_zero(pp, p), a1 = a0 | (1 << p);
        float2 u0 = U[a0 * 16 + j], u1 = U[a1 * 16 + j];
        U[a0 * 16 + j] = make_float2(c * u0.x - s * u1.x, c * u0.y - s * u1.y);
        U[a1 * 16 + j] = make_float2(s * u0.x + c * u1.x, s * u0.y + c * u1.y);
      }
      __syncthreads();
      sincosf(0.5f * prep[ly * 8 + qi * 2 + 1], &s, &c);
      for (int it = lane; it < 128; it += 64) {
        int j = it & 15, pp = it >> 4;
        int a0 = insert_zero(pp, p), a1 = a0 | (1 << p);
        float2 u0 = U[a0 * 16 + j], u1 = U[a1 * 16 + j];
        U[a0 * 16 + j] = make_float2(c * u0.x + s * u0.y, c * u0.y - s * u0.x);
        U[a1 * 16 + j] = make_float2(c * u1.x - s * u1.y, c * u1.y + s * u1.x);
      }
      __syncthreads();
    }
    for (int i = 0; i < 3; ++i) {
      int pc = 3 - i, pt = 2 - i;
      {
        int j = lane & 15, pp = lane >> 4;     // exactly 64 items
        int m = insert_zero(pp, pt);
        m = insert_zero(m, pc);
        int a0 = m | (1 << pc), a1 = a0 | (1 << pt);
        float2 t0 = U[a0 * 16 + j], t1 = U[a1 * 16 + j];
        U[a0 * 16 + j] = t1;
        U[a1 * 16 + j] = t0;
      }
      __syncthreads();
    }
  }

  // ---- phase 0c: per-block matrix rows + qsc + init scalar ----
  float2 e0, e1, e2, e3;
  sincosf(sig[0], &e0.y, &e0.x);
  sincosf(sig[1], &e1.y, &e1.x);
  sincosf(sig[2], &e2.y, &e2.x);
  sincosf(sig[3], &e3.y, &e3.x);
  if (lane < 16) {
    float2 acc1 = make_float2(0.f, 0.f), acc2 = make_float2(0.f, 0.f);
    for (int cix = 0; cix < 16; ++cix) {
      float2 t = cmul(U[aa * 16 + cix], conj2(U[lane * 16 + cix]));
      acc1 = cfma(t, (cix == 0) ? e1 : conj2(e1), acc1);
      acc2 = cfma(t, (cix == 0) ? e2 : conj2(e2), acc2);
    }
    m1row[lane] = acc1;                         // (U D1 U^dag)[aa][lane]
    m2row[lane] = acc2;                         // (U D2 U^dag)[aa][lane]
    float2 v3 = (aa == 0) ? e3 : conj2(e3);
    mendrow[lane] = cmul(v3, conj2(U[lane * 16 + aa]));   // (D3 U^dag)[aa][lane]
  }
  if (lane < 40) {
    float s, c;
    sincosf(0.5f * qff[lane], &s, &c);
    qscs[lane] = make_float2(s, c);
  }
  float2 m0 = cmul(U[aa * 16 + 0], e0);         // (U D0)[aa][0] * e^{i sig0}
  __syncthreads();

  const float2* sc = scs;
  float2 a[16];

  // ---- phase 1: init |0..0> column + select fwd ----
#pragma unroll
  for (int r = 0; r < 16; ++r) a[r] = make_float2(0.f, 0.f);
  if (lane == 0) a[0] = m0;
  run_layer<false>(a, sc, lane);
  run_layer<false>(a, sc + 40, lane);
  store_col(state0, blk, lane, a);
  group_barrier(b);

  // ---- phase 2: mix M1 + select adjoint ----
  mix_load_row(a, state0, m1row, b, lane);
  run_layer<true>(a, sc + 40, lane);
  run_layer<true>(a, sc, lane);
  store_col(state1, blk, lane, a);
  group_barrier(b);

  // ---- phase 3: mix M2 + select fwd ----
  mix_load_row(a, state1, m2row, b, lane);
  run_layer<false>(a, sc, lane);
  run_layer<false>(a, sc + 40, lane);
  store_col(state0, blk, lane, a);
  group_barrier(b);

  // ---- phase 4: mix Mend + qff + expvals partials ----
  mix_load_row(a, state0, mendrow, b, lane);
  run_layer<false>(a, qscs, lane);
  {
    float obs[30];
#pragma unroll
    for (int p = 0; p <= 9; ++p) {
      int i = 9 - p;
      float cr = 0.f, ci = 0.f, zz = 0.f;
      if (p < 4) {
        int m = 1 << p;
#pragma unroll
        for (int r0 = 0; r0 < 16; ++r0) {
          if (!(r0 & m)) {
            float2 A0 = a[r0], A1 = a[r0 | m];
            cr += A0.x * A1.x + A0.y * A1.y;
            ci += A0.x * A1.y - A0.y * A1.x;
            zz += (A0.x * A0.x + A0.y * A0.y) - (A1.x * A1.x + A1.y * A1.y);
          }
        }
      } else {
        int xm = 1 << (p - 4);
        bool up = (lane >> (p - 4)) & 1;
#pragma unroll
        for (int r = 0; r < 16; ++r) {
          float wx = __shfl_xor(a[r].x, xm, 64);
          float wy = __shfl_xor(a[r].y, xm, 64);
          float n2 = a[r].x * a[r].x + a[r].y * a[r].y;
          if (!up) {
            cr += a[r].x * wx + a[r].y * wy;
            ci += a[r].x * wy - a[r].y * wx;
            zz += n2;
          } else {
            zz -= n2;
          }
        }
      }
      obs[i] = 2.f * cr;
      obs[10 + i] = 2.f * ci;
      obs[20 + i] = zz;
    }
#pragma unroll
    for (int j = 0; j < 30; ++j) {
      float v = obs[j];
      for (int off = 32; off; off >>= 1) v += __shfl_down(v, off, 64);
      if (lane == 0) atomicAdd(&sv[b * 30 + j], v);
    }
  }

  // ---- phase 5: last-arriving block of group b computes its output row ----
  int lastflag = 0;
  if (lane == 0) {
    unsigned old = __hip_atomic_fetch_add(&g_gb[b].done, 1u, __ATOMIC_ACQ_REL,
                                          __HIP_MEMORY_SCOPE_AGENT);
    lastflag = ((old & 15u) == 15u) ? 1 : 0;
  }
  lastflag = __shfl(lastflag, 0, 64);
  if (lastflag) {
    (void)__hip_atomic_load(&g_gb[b].done, __ATOMIC_ACQUIRE, __HIP_MEMORY_SCOPE_AGENT);
    if (lane < 8) {
      float acc = b_out[lane];
#pragma unroll
      for (int j = 0; j < 30; ++j) acc += W_out[lane * 30 + j] * sv[b * 30 + j];
      out[b * 8 + lane] = acc;
    }
  }
}

// ================= fallback multi-kernel path (ws too small) =================

__global__ __launch_bounds__(128) void k_ts(const float* __restrict__ x,
                                            const float* __restrict__ W,
                                            const float* __restrict__ bias,
                                            float2* __restrict__ tsc) {
  int blk = blockIdx.x;
  int b = blk >> 4, t = blk & 15;
  __shared__ float h[64];
  int tid = threadIdx.x;
  if (tid < 64) {
    int f = tid, k = f >> 1;
    float div = expf(-(float)(2 * k) * (logf(10000.f) / 64.f));
    float ang = (float)t * div;
    float pe = (f & 1) ? cosf(ang) : sinf(ang);
    h[f] = x[(b * 64 + f) * 16 + t] + pe;
  }
  __syncthreads();
  if (tid < 80) {
    float acc = bias[tid];
    const float* wr = W + tid * 64;
#pragma unroll 8
    for (int f = 0; f < 64; ++f) acc += h[f] * wr[f];
    float sg = 1.f / (1.f + expf(-acc));
    float s, c;
    sincosf(sg * 3.14159265358979323846f, &s, &c);
    tsc[blk * 80 + tid] = make_float2(s, c);
  }
}

__global__ __launch_bounds__(256) void k_build(const float* __restrict__ prep,
                                               const float* __restrict__ sig,
                                               const float* __restrict__ qffp,
                                               float2* __restrict__ mats,
                                               float2* __restrict__ qsc) {
  __shared__ float2 U[256];
  int tid = threadIdx.x;
  if (tid < 40) {
    float s, c;
    sincosf(0.5f * qffp[tid], &s, &c);
    qsc[tid] = make_float2(s, c);
  }
  U[tid] = make_float2((tid >> 4) == (tid & 15) ? 1.f : 0.f, 0.f);
  __syncthreads();
  for (int ly = 0; ly < 4; ++ly) {
    for (int qi = 0; qi < 4; ++qi) {
      int p = 3 - qi;
      float th = prep[ly * 8 + qi * 2 + 0];
      float s, c;
      sincosf(0.5f * th, &s, &c);
      if (tid < 128) {
        int j = tid & 15, pp = tid >> 4;
        int a0 = insert_zero(pp, p), a1 = a0 | (1 << p);
        float2 u0 = U[a0 * 16 + j], u1 = U[a1 * 16 + j];
        U[a0 * 16 + j] = make_float2(c * u0.x - s * u1.x, c * u0.y - s * u1.y);
        U[a1 * 16 + j] = make_float2(s * u0.x + c * u1.x, s * u0.y + c * u1.y);
      }
      __syncthreads();
      th = prep[ly * 8 + qi * 2 + 1];
      sincosf(0.5f * th, &s, &c);
      if (tid < 128) {
        int j = tid & 15, pp = tid >> 4;
        int a0 = insert_zero(pp, p), a1 = a0 | (1 << p);
        float2 u0 = U[a0 * 16 + j], u1 = U[a1 * 16 + j];
        U[a0 * 16 + j] = make_float2(c * u0.x + s * u0.y, c * u0.y - s * u0.x);
        U[a1 * 16 + j] = make_float2(c * u1.x - s * u1.y, c * u1.y + s * u1.x);
      }
      __syncthreads();
    }
    for (int i = 0; i < 3; ++i) {
      int pc = 3 - i, pt = 2 - i;
      if (tid < 64) {
        int j = tid & 15, pp = tid >> 4;
        int m = insert_zero(pp, pt);
        m = insert_zero(m, pc);
        int a0 = m | (1 << pc), a1 = a0 | (1 << pt);
        float2 t0 = U[a0 * 16 + j], t1 = U[a1 * 16 + j];
        U[a0 * 16 + j] = t1;
        U[a1 * 16 + j] = t0;
      }
      __syncthreads();
    }
  }
  int a = tid >> 4, bb = tid & 15;
  float2 e1, e2, e3;
  sincosf(sig[1], &e1.y, &e1.x);
  sincosf(sig[2], &e2.y, &e2.x);
  sincosf(sig[3], &e3.y, &e3.x);
  float2 acc1 = make_float2(0.f, 0.f), acc2 = make_float2(0.f, 0.f);
  for (int cix = 0; cix < 16; ++cix) {
    float2 t = cmul(U[a * 16 + cix], conj2(U[bb * 16 + cix]));
    acc1 = cfma(t, (cix == 0) ? e1 : conj2(e1), acc1);
    acc2 = cfma(t, (cix == 0) ? e2 : conj2(e2), acc2);
  }
  mats[16 + tid] = acc1;
  mats[272 + tid] = acc2;
  float2 v3 = (a == 0) ? e3 : conj2(e3);
  mats[528 + tid] = cmul(v3, conj2(U[bb * 16 + a]));
  if (tid < 16) {
    float2 e0;
    sincosf(sig[0], &e0.y, &e0.x);
    mats[tid] = cmul(U[tid * 16 + 0], e0);
  }
}

template<bool ADJ, int MODE>
__global__ __launch_bounds__(64) void k_sel(const float2* __restrict__ src,
                                            float2* __restrict__ dst,
                                            const float2* __restrict__ sc_ts,
                                            const float2* __restrict__ mat) {
  int blk = blockIdx.x, lane = threadIdx.x;
  const float2* __restrict__ sc = sc_ts + blk * 80;
  float2 a[16];
  if constexpr (MODE == 0) {
#pragma unroll
    for (int r = 0; r < 16; ++r) a[r] = make_float2(0.f, 0.f);
    if (lane == 0) a[0] = mat[blk & 15];
  } else if constexpr (MODE == 1) {
    const float4* g4 = (const float4*)(src + (size_t)blk * 1024) + lane * 8;
#pragma unroll
    for (int q = 0; q < 8; ++q) {
      float4 v = g4[q];
      a[2 * q]     = make_float2(v.x, v.y);
      a[2 * q + 1] = make_float2(v.z, v.w);
    }
  } else {
    mix_load(a, src, mat, blk >> 4, blk & 15, lane);
  }
  if constexpr (ADJ) {
    run_layer<true>(a, sc + 40, lane);
    run_layer<true>(a, sc, lane);
  } else {
    run_layer<false>(a, sc, lane);
    run_layer<false>(a, sc + 40, lane);
  }
  store_col(dst, blk, lane, a);
}

__global__ __launch_bounds__(64) void k_qff_exp(const float2* __restrict__ src,
                                                const float2* __restrict__ mend,
                                                const float2* __restrict__ qsc,
                                                float* __restrict__ sv) {
  int blk = blockIdx.x, lane = threadIdx.x;
  int b = blk >> 4, aa = blk & 15;
  float2 a[16];
  mix_load(a, src, mend, b, aa, lane);
  run_layer<false>(a, qsc, lane);
  float obs[30];
#pragma unroll
  for (int p = 0; p <= 9; ++p) {
    int i = 9 - p;
    float cr = 0.f, ci = 0.f, zz = 0.f;
    if (p < 4) {
      int m = 1 << p;
#pragma unroll
      for (int r0 = 0; r0 < 16; ++r0) {
        if (!(r0 & m)) {
          float2 A0 = a[r0], A1 = a[r0 | m];
          cr += A0.x * A1.x + A0.y * A1.y;
          ci += A0.x * A1.y - A0.y * A1.x;
          zz += (A0.x * A0.x + A0.y * A0.y) - (A1.x * A1.x + A1.y * A1.y);
        }
      }
    } else {
      int xm = 1 << (p - 4);
      bool up = (lane >> (p - 4)) & 1;
#pragma unroll
      for (int r = 0; r < 16; ++r) {
        float wx = __shfl_xor(a[r].x, xm, 64);
        float wy = __shfl_xor(a[r].y, xm, 64);
        float n2 = a[r].x * a[r].x + a[r].y * a[r].y;
        if (!up) {
          cr += a[r].x * wx + a[r].y * wy;
          ci += a[r].x * wy - a[r].y * wx;
          zz += n2;
        } else {
          zz -= n2;
        }
      }
    }
    obs[i] = 2.f * cr;
    obs[10 + i] = 2.f * ci;
    obs[20 + i] = zz;
  }
#pragma unroll
  for (int j = 0; j < 30; ++j) {
    float v = obs[j];
    for (int off = 32; off; off >>= 1) v += __shfl_down(v, off, 64);
    if (lane == 0) atomicAdd(&sv[b * 30 + j], v);
  }
}

__global__ __launch_bounds__(128) void k_out(const float* __restrict__ sv,
                                             const float* __restrict__ W,
                                             const float* __restrict__ bo,
                                             float* __restrict__ out) {
  int tid = threadIdx.x;
  int b = tid >> 3, o = tid & 7;
  float acc = bo[o];
#pragma unroll
  for (int j = 0; j < 30; ++j) acc += W[o * 30 + j] * sv[b * 30 + j];
  out[tid] = acc;
}

__global__ __launch_bounds__(256) void k_anc(float2* __restrict__ state,
                                             const float2* __restrict__ M) {
  __shared__ float2 sM[256];
  int tid = threadIdx.x;
  sM[tid] = M[tid];
  __syncthreads();
  int t = blockIdx.x * 256 + tid;
  int b = t >> 10, n = t & 1023;
  float2* p = state + b * 16384 + n;
  float2 v[16];
#pragma unroll
  for (int ap = 0; ap < 16; ++ap) v[ap] = p[ap << 10];
#pragma unroll
  for (int ao = 0; ao < 16; ++ao) {
    float re = 0.f, im = 0.f;
#pragma unroll
    for (int ap = 0; ap < 16; ++ap) {
      float2 m = sM[ao * 16 + ap];
      re += m.x * v[ap].x - m.y * v[ap].y;
      im += m.x * v[ap].y + m.y * v[ap].x;
    }
    p[ao << 10] = make_float2(re, im);
  }
}

extern "C" void kernel_launch(void* const* d_in, const int* in_sizes, int n_in,
                              void* d_out, int out_size, void* d_ws, size_t ws_size,
                              hipStream_t stream) {
  const float* x     = (const float*)d_in[0];
  const float* W_fp  = (const float*)d_in[1];
  const float* b_fp  = (const float*)d_in[2];
  const float* prep  = (const float*)d_in[3];
  const float* sig   = (const float*)d_in[4];
  const float* qff   = (const float*)d_in[5];
  const float* W_out = (const float*)d_in[6];
  const float* b_out = (const float*)d_in[7];
  float* out = (float*)d_out;

  char* ws = (char*)d_ws;
  const size_t SZ_STATE = 2097152;      // 256 cols * 1024 * 8 B
  const size_t SZ_SV    = 1920;         // 16*30 float

  if (ws_size >= 2 * SZ_STATE + SZ_SV) {
    // fused single-dispatch path (normal launch; per-b group barriers inside)
    float2* state0 = (float2*)ws;
    float2* state1 = (float2*)(ws + SZ_STATE);
    float*  sv     = (float*)(ws + 2 * SZ_STATE);
    k_fused<<<dim3(256), dim3(64), 0, stream>>>(x, W_fp, b_fp, prep, sig, qff,
                                                W_out, b_out, out, state0, state1, sv);
    return;
  }

  // fallback multi-kernel path (original structure)
  const size_t SZ_TSC   = 163840;
  const size_t SZ_MATS  = 6272;
  const size_t SZ_QSC   = 320;
  bool pp = ws_size >= 2 * SZ_STATE + SZ_TSC + SZ_MATS + SZ_QSC + SZ_SV;

  float2* state0 = (float2*)ws;
  float2* state1 = pp ? (float2*)(ws + SZ_STATE) : nullptr;
  char* tail = ws + (pp ? 2 * SZ_STATE : SZ_STATE);
  float2* tsc  = (float2*)tail;
  float2* mats = (float2*)(tail + SZ_TSC);
  float2* qsc  = (float2*)(tail + SZ_TSC + SZ_MATS);
  float*  sv   = (float*) (tail + SZ_TSC + SZ_MATS + SZ_QSC);

  hipMemsetAsync(sv, 0, SZ_SV, stream);
  k_ts<<<256, 128, 0, stream>>>(x, W_fp, b_fp, tsc);
  k_build<<<1, 256, 0, stream>>>(prep, sig, qff, mats, qsc);

  if (pp) {
    k_sel<false, 0><<<256, 64, 0, stream>>>(nullptr, state0, tsc, mats);
    k_sel<true,  2><<<256, 64, 0, stream>>>(state0, state1, tsc, mats + 16);
    k_sel<false, 2><<<256, 64, 0, stream>>>(state1, state0, tsc, mats + 272);
  } else {
    k_sel<false, 0><<<256, 64, 0, stream>>>(nullptr, state0, tsc, mats);
    k_anc<<<64, 256, 0, stream>>>(state0, mats + 16);
    k_sel<true,  1><<<256, 64, 0, stream>>>(state0, state0, tsc, nullptr);
    k_anc<<<64, 256, 0, stream>>>(state0, mats + 272);
    k_sel<false, 1><<<256, 64, 0, stream>>>(state0, state0, tsc, nullptr);
  }
  k_qff_exp<<<256, 64, 0, stream>>>(state0, mats + 528, qsc, sv);
  k_out<<<1, 128, 0, stream>>>(sv, W_out, b_out, out);
}

// Round 5
// 186.462 us; speedup vs baseline: 1.7041x; 1.1511x over previous
//
#include <hip/hip_runtime.h>
#include <math.h>
#include <utility>

// B=16, T=16, FDIM=64, ODIM=8, NQ=10, NA=4, LAYERS=2, DEGREE=3.
// State: one wave owns one (b,a) column of 1024 complex amps in registers.
// Amp mapping: n = lane*16 + r  (bits [3:0]=r in-thread, [9:4]=lane).
// Gates on bit<4: thread-local. Gates on bit>=4: cross-lane butterfly
//   (xor1/2/8 -> DPP, xor4/16/32 -> __shfl_xor).
//
// KEY ALGEBRA (round 5):
//  - pcphase D_k = conj(e_k) I + (e_k-conj(e_k))|0><0|  =>  ancilla mix
//    M_k = U D_k U^dag = conj(e_k) I + (e_k-conj(e_k)) u0 u0^dag  (RANK-1,
//    u0 = U|0>). Cross-column coupling is one projection s = u0^dag . cols:
//    each wave stores p = conj(u0[aa]) * col (8 KB, coalesced float4),
//    barrier, reads the 16 partials coalesced, col <- conj(e) col + w s.
//  - Mend = D3 U^dag is UNITARY on the ancilla index; qff + observables act
//    only on the NQ index and expvals trace over ancilla => the final mix
//    drops out exactly. Phase-4 mix + store + 3rd barrier deleted.
//  - Only u0 is needed, not U: per-lane 16-complex register evolution of
//    |0>_anc (prep sincos staged once across lanes). No LDS U-build.
//
// Cross-block sync: per-b groups of 16 blocks (monotonic cnt/gen words,
// relaxed polls + single acquire) -- structure proven in rounds 3/4.

struct Gate { int ry; int tbit; int cbit; int pidx; };
struct GateTab { Gate g[40]; };

constexpr GateTab make_gates1() {
  GateTab tb{};
  int pos = 0, idx = 0;
  for (int i = 0; i < 10; ++i) { tb.g[pos] = Gate{1, 9 - i, -1, idx}; ++pos; ++idx; }
  for (int i = 9; i >= 0; --i) { tb.g[pos] = Gate{0, 9 - ((i + 1) % 10), 9 - i, idx}; ++pos; ++idx; }
  for (int i = 0; i < 10; ++i) { tb.g[pos] = Gate{1, 9 - i, -1, idx}; ++pos; ++idx; }
  for (int k = 0; k < 10; ++k) {
    int i = (k == 0) ? 9 : (k - 1);
    tb.g[pos] = Gate{0, 9 - ((i + 9) % 10), 9 - i, idx}; ++pos; ++idx;
  }
  return tb;
}
constexpr GateTab GTC = make_gates1();

__device__ __forceinline__ int insert_zero(int v, int p) {
  return ((v >> p) << (p + 1)) | (v & ((1 << p) - 1));
}
__device__ __forceinline__ float2 cmul(float2 A, float2 B) {
  return make_float2(A.x * B.x - A.y * B.y, A.x * B.y + A.y * B.x);
}
__device__ __forceinline__ float2 conj2(float2 A) { return make_float2(A.x, -A.y); }
__device__ __forceinline__ float2 cfma(float2 A, float2 B, float2 acc) {
  acc.x += A.x * B.x - A.y * B.y;
  acc.y += A.x * B.y + A.y * B.x;
  return acc;
}

// ---------------- cross-lane xor: DPP where possible ----------------
template<int XM>
__device__ __forceinline__ float lxor(float v) {
  if constexpr (XM == 1) {
    int r = __builtin_amdgcn_update_dpp(__float_as_int(v), __float_as_int(v),
                                        0xB1, 0xF, 0xF, true);
    return __int_as_float(r);
  } else if constexpr (XM == 2) {
    int r = __builtin_amdgcn_update_dpp(__float_as_int(v), __float_as_int(v),
                                        0x4E, 0xF, 0xF, true);
    return __int_as_float(r);
  } else if constexpr (XM == 8) {
    int r = __builtin_amdgcn_update_dpp(__float_as_int(v), __float_as_int(v),
                                        0x128, 0xF, 0xF, true);
    return __int_as_float(r);
  } else {
    return __shfl_xor(v, XM, 64);
  }
}

// ---------------- per-b group barrier (16 participants) ----------------
struct alignas(128) GBar {
  unsigned cnt;        // barrier arrivals, monotonic
  unsigned gen;        // completed barrier rounds, monotonic
  unsigned done;       // phase-final completions, monotonic
  unsigned pad[29];
};
__device__ GBar g_gb[16];

__device__ __forceinline__ void group_barrier(int b) {
  unsigned snap = __hip_atomic_load(&g_gb[b].gen, __ATOMIC_RELAXED, __HIP_MEMORY_SCOPE_AGENT);
  if (threadIdx.x == 0) {
    unsigned old = __hip_atomic_fetch_add(&g_gb[b].cnt, 1u, __ATOMIC_ACQ_REL,
                                          __HIP_MEMORY_SCOPE_AGENT);
    if ((old & 15u) == 15u)
      __hip_atomic_store(&g_gb[b].gen, snap + 1u, __ATOMIC_RELEASE,
                         __HIP_MEMORY_SCOPE_AGENT);
  }
  while (__hip_atomic_load(&g_gb[b].gen, __ATOMIC_RELAXED, __HIP_MEMORY_SCOPE_AGENT) == snap)
    __builtin_amdgcn_s_sleep(1);
  (void)__hip_atomic_load(&g_gb[b].gen, __ATOMIC_ACQUIRE, __HIP_MEMORY_SCOPE_AGENT);
}

// ---------------- register/shuffle gate engine ----------------
template<int P>
__device__ __forceinline__ void ry_gate(float2 (&a)[16], float c, float s, int lane) {
  if constexpr (P < 4) {
    constexpr int m = 1 << P;
#pragma unroll
    for (int r0 = 0; r0 < 16; ++r0) {
      if (!(r0 & m)) {
        int r1 = r0 | m;
        float2 a0 = a[r0], a1 = a[r1];
        a[r0] = make_float2(c * a0.x - s * a1.x, c * a0.y - s * a1.y);
        a[r1] = make_float2(s * a0.x + c * a1.x, s * a0.y + c * a1.y);
      }
    }
  } else {
    constexpr int xm = 1 << (P - 4);
    bool up = (lane >> (P - 4)) & 1;
    float sg = up ? s : -s;
#pragma unroll
    for (int r = 0; r < 16; ++r) {
      float wx = lxor<xm>(a[r].x);
      float wy = lxor<xm>(a[r].y);
      a[r].x = c * a[r].x + sg * wx;
      a[r].y = c * a[r].y + sg * wy;
    }
  }
}

template<int P, int Q>
__device__ __forceinline__ void crx_gate(float2 (&a)[16], float c, float s, int lane) {
  if constexpr (P < 4) {
    constexpr int m = 1 << P;
#pragma unroll
    for (int r0 = 0; r0 < 16; ++r0) {
      if (!(r0 & m)) {
        int r1 = r0 | m;
        bool act;
        if constexpr (Q < 4) act = (r0 >> Q) & 1;
        else act = (lane >> (Q - 4)) & 1;
        if (act) {
          float2 a0 = a[r0], a1 = a[r1];
          a[r0] = make_float2(c * a0.x + s * a1.y, c * a0.y - s * a1.x);
          a[r1] = make_float2(c * a1.x + s * a0.y, c * a1.y - s * a0.x);
        }
      }
    }
  } else {
    constexpr int xm = 1 << (P - 4);
#pragma unroll
    for (int r = 0; r < 16; ++r) {
      float wx = lxor<xm>(a[r].x);
      float wy = lxor<xm>(a[r].y);
      bool act;
      if constexpr (Q < 4) act = (r >> Q) & 1;
      else act = (lane >> (Q - 4)) & 1;
      if (act) {
        float nx = c * a[r].x + s * wy;
        float ny = c * a[r].y - s * wx;
        a[r].x = nx; a[r].y = ny;
      }
    }
  }
}

template<bool ADJ, int G>
__device__ __forceinline__ void one_gate(float2 (&a)[16], const float2 (&sc)[40], int lane) {
  constexpr Gate g = GTC.g[ADJ ? (39 - G) : G];
  float2 scv = sc[g.pidx];
  float s = ADJ ? -scv.x : scv.x;
  float c = scv.y;
  if constexpr (g.ry != 0) ry_gate<g.tbit>(a, c, s, lane);
  else crx_gate<g.tbit, g.cbit>(a, c, s, lane);
}

template<bool ADJ, int... I>
__device__ __forceinline__ void run_layer_impl(float2 (&a)[16], const float2 (&sc)[40],
                                               int lane, std::integer_sequence<int, I...>) {
  (one_gate<ADJ, I>(a, sc, lane), ...);
}

template<bool ADJ>
__device__ __forceinline__ void run_layer(float2 (&a)[16], const float2* sc, int lane) {
  float2 rsc[40];
#pragma unroll
  for (int i = 0; i < 40; ++i) rsc[i] = sc[i];
  run_layer_impl<ADJ>(a, rsc, lane, std::make_integer_sequence<int, 40>{});
}

// ---------------- rank-1 mix helpers (coalesced float4 layout) ----------------
// partial buffer layout per column: float4 P[blk][q*64 + lane], q<8,
// P = (p[2q].x, p[2q].y, p[2q+1].x, p[2q+1].y), p[r] = cu * a[r].
__device__ __forceinline__ void store_partial(const float2 (&a)[16], float4* __restrict__ dst_col,
                                              int lane, float2 cu) {
#pragma unroll
  for (int q = 0; q < 8; ++q) {
    float2 p0 = cmul(cu, a[2 * q]);
    float2 p1 = cmul(cu, a[2 * q + 1]);
    dst_col[q * 64 + lane] = make_float4(p0.x, p0.y, p1.x, p1.y);
  }
}

// col <- ce*col + w*s, s = sum over the 16 sibling partials (coalesced reads)
__device__ __forceinline__ void mix_rank1(float2 (&a)[16], const float4* __restrict__ part,
                                          int b, int lane, float2 ce, float2 w) {
  float4 s[8];
#pragma unroll
  for (int q = 0; q < 8; ++q) s[q] = make_float4(0.f, 0.f, 0.f, 0.f);
#pragma unroll
  for (int ap = 0; ap < 16; ++ap) {
    const float4* col = part + (size_t)(b * 16 + ap) * 512 + lane;
#pragma unroll
    for (int q = 0; q < 8; ++q) {
      float4 v = col[q * 64];
      s[q].x += v.x; s[q].y += v.y; s[q].z += v.z; s[q].w += v.w;
    }
  }
#pragma unroll
  for (int q = 0; q < 8; ++q) {
    float2 a0 = a[2 * q], a1 = a[2 * q + 1];
    a[2 * q] = make_float2(ce.x * a0.x - ce.y * a0.y + w.x * s[q].x - w.y * s[q].y,
                           ce.x * a0.y + ce.y * a0.x + w.x * s[q].y + w.y * s[q].x);
    a[2 * q + 1] = make_float2(ce.x * a1.x - ce.y * a1.y + w.x * s[q].z - w.y * s[q].w,
                               ce.x * a1.y + ce.y * a1.x + w.x * s[q].w + w.y * s[q].z);
  }
}

// Old-style mix (full matrix in global) for the fallback path.
__device__ __forceinline__ void mix_load(float2 (&a)[16], const float2* __restrict__ src,
                                         const float2* __restrict__ M, int b, int aa, int lane) {
#pragma unroll
  for (int r = 0; r < 16; ++r) a[r] = make_float2(0.f, 0.f);
#pragma unroll
  for (int ap = 0; ap < 16; ++ap) {
    float2 m = M[aa * 16 + ap];
    const float4* col4 = (const float4*)(src + (size_t)(b * 16 + ap) * 1024) + lane * 8;
#pragma unroll
    for (int q = 0; q < 8; ++q) {
      float4 v = col4[q];
      a[2 * q].x     += m.x * v.x - m.y * v.y;
      a[2 * q].y     += m.x * v.y + m.y * v.x;
      a[2 * q + 1].x += m.x * v.z - m.y * v.w;
      a[2 * q + 1].y += m.x * v.w + m.y * v.z;
    }
  }
}

__device__ __forceinline__ void store_col(float2* dst, int blk, int lane, float2 (&a)[16]) {
  float4* o4 = (float4*)(dst + (size_t)blk * 1024) + lane * 8;
#pragma unroll
  for (int q = 0; q < 8; ++q)
    o4[q] = make_float4(a[2 * q].x, a[2 * q].y, a[2 * q + 1].x, a[2 * q + 1].y);
}

// ---------------- the fused kernel ----------------
__global__ __launch_bounds__(64, 1) void k_fused(const float* __restrict__ x,
                                                 const float* __restrict__ W_fp,
                                                 const float* __restrict__ b_fp,
                                                 const float* __restrict__ prep,
                                                 const float* __restrict__ sig,
                                                 const float* __restrict__ qff,
                                                 const float* __restrict__ W_out,
                                                 const float* __restrict__ b_out,
                                                 float* __restrict__ out,
                                                 float4* __restrict__ part1,
                                                 float4* __restrict__ part2,
                                                 float* __restrict__ sv) {
  int blk = blockIdx.x, lane = threadIdx.x;     // blk = b*16 + a
  int b = blk >> 4, aa = blk & 15;

  __shared__ __align__(16) float h[64];
  __shared__ float2 scs[80];                    // ts (sin,cos) for this column (t = aa)
  __shared__ float2 qscs[40];                   // qff (sin,cos)
  __shared__ float2 ps[32];                     // prep (sin,cos) of th/2
  __shared__ float2 es[4];                      // e^{i sig_k} = (cos, sin)

  // sv zeroing for this b (ordered before final adds via barrier chain)
  if (aa == 0 && lane < 30) sv[b * 30 + lane] = 0.f;

  // ---- phase 0a: ts params for (b, t = aa) ----
  {
    int t = aa;
    int f = lane, k = f >> 1;
    float div = expf(-(float)(2 * k) * (logf(10000.f) / 64.f));
    float ang = (float)t * div;
    float pe = (f & 1) ? cosf(ang) : sinf(ang);
    h[f] = x[(b * 64 + f) * 16 + t] + pe;
  }
  // stage small sincos tables in parallel with the h barrier
  if (lane < 32) {
    float s, c;
    sincosf(0.5f * prep[lane], &s, &c);         // prep[ly*8+qi*2+k] == prep[lane]
    ps[lane] = make_float2(s, c);
  } else if (lane < 36) {
    float s, c;
    sincosf(sig[lane - 32], &s, &c);
    es[lane - 32] = make_float2(c, s);          // complex exp (cos, sin)
  }
  if (lane < 40) {
    float s, c;
    sincosf(0.5f * qff[lane], &s, &c);
    qscs[lane] = make_float2(s, c);
  }
  __syncthreads();
  {
    const float4* h4 = (const float4*)h;
    for (int j = lane; j < 80; j += 64) {
      float acc = b_fp[j];
      const float4* w4 = (const float4*)(W_fp + j * 64);
#pragma unroll
      for (int k4 = 0; k4 < 16; ++k4) {
        float4 hh = h4[k4], ww = w4[k4];
        acc += hh.x * ww.x + hh.y * ww.y + hh.z * ww.z + hh.w * ww.w;
      }
      float sg = 1.f / (1.f + expf(-acc));
      float s, c;
      sincosf(sg * 3.14159265358979323846f, &s, &c);   // theta/2 = sigmoid*pi
      scs[j] = make_float2(s, c);
    }
  }

  // ---- phase 0b: u0 = (prepare circuit)|0>_anc, 16 complex, per-lane regs ----
  float2 v[16];
#pragma unroll
  for (int i = 0; i < 16; ++i) v[i] = make_float2(i == 0 ? 1.f : 0.f, 0.f);
  for (int ly = 0; ly < 4; ++ly) {
#pragma unroll
    for (int qi = 0; qi < 4; ++qi) {
      int p = 3 - qi;
      float2 rc = ps[ly * 8 + qi * 2 + 0];      // ry
      {
        float s = rc.x, c = rc.y;
#pragma unroll
        for (int m = 0; m < 8; ++m) {
          int a0 = insert_zero(m, p), a1 = a0 | (1 << p);
          float2 t0 = v[a0], t1 = v[a1];
          v[a0] = make_float2(c * t0.x - s * t1.x, c * t0.y - s * t1.y);
          v[a1] = make_float2(s * t0.x + c * t1.x, s * t0.y + c * t1.y);
        }
      }
      rc = ps[ly * 8 + qi * 2 + 1];             // rz
      {
        float s = rc.x, c = rc.y;
#pragma unroll
        for (int m = 0; m < 8; ++m) {
          int a0 = insert_zero(m, p), a1 = a0 | (1 << p);
          float2 t0 = v[a0], t1 = v[a1];
          v[a0] = make_float2(c * t0.x + s * t0.y, c * t0.y - s * t0.x);   // * e^{-i th/2}
          v[a1] = make_float2(c * t1.x - s * t1.y, c * t1.y + s * t1.x);   // * e^{+i th/2}
        }
      }
    }
#pragma unroll
    for (int i = 0; i < 3; ++i) {
      int pc = 3 - i, pt = 2 - i;
#pragma unroll
      for (int m = 0; m < 4; ++m) {
        int mm = insert_zero(m, pt);
        mm = insert_zero(mm, pc);
        int a0 = mm | (1 << pc), a1 = a0 | (1 << pt);
        float2 t0 = v[a0], t1 = v[a1];
        v[a0] = t1; v[a1] = t0;
      }
    }
  }
  // select u0[aa] (runtime index -> unrolled cndmask, no scratch)
  float2 u0aa = make_float2(0.f, 0.f);
#pragma unroll
  for (int i = 0; i < 16; ++i) if (aa == i) u0aa = v[i];

  float2 e0 = es[0], e1 = es[1], e2 = es[2];
  float2 m0  = cmul(u0aa, e0);                  // (U D0)[aa][0] * e^{i sig0}
  float2 cu0 = conj2(u0aa);
  float2 ce1 = conj2(e1);
  float2 w1  = make_float2(-2.f * e1.y * u0aa.y, 2.f * e1.y * u0aa.x);  // (e1-e1*)u0[aa]
  float2 ce2 = conj2(e2);
  float2 w2  = make_float2(-2.f * e2.y * u0aa.y, 2.f * e2.y * u0aa.x);
  __syncthreads();

  const float2* sc = scs;
  float2 a[16];

  // ---- phase 1: init |0..0> column + select fwd ----
#pragma unroll
  for (int r = 0; r < 16; ++r) a[r] = make_float2(0.f, 0.f);
  if (lane == 0) a[0] = m0;
  run_layer<false>(a, sc, lane);
  run_layer<false>(a, sc + 40, lane);
  store_partial(a, part1 + (size_t)blk * 512, lane, cu0);
  group_barrier(b);

  // ---- phase 2: rank-1 mix M1 + select adjoint ----
  mix_rank1(a, part1, b, lane, ce1, w1);
  run_layer<true>(a, sc + 40, lane);
  run_layer<true>(a, sc, lane);
  store_partial(a, part2 + (size_t)blk * 512, lane, cu0);
  group_barrier(b);

  // ---- phase 3: rank-1 mix M2 + select fwd ----
  mix_rank1(a, part2, b, lane, ce2, w2);
  run_layer<false>(a, sc, lane);
  run_layer<false>(a, sc + 40, lane);

  // ---- phase 4: qff + expvals (Mend mix deleted: unitary on ancilla) ----
  run_layer<false>(a, qscs, lane);
  {
    float obs[30];
#pragma unroll
    for (int p = 0; p <= 9; ++p) {
      int i = 9 - p;
      float cr = 0.f, ci = 0.f, zz = 0.f;
      if (p < 4) {
        int m = 1 << p;
#pragma unroll
        for (int r0 = 0; r0 < 16; ++r0) {
          if (!(r0 & m)) {
            float2 A0 = a[r0], A1 = a[r0 | m];
            cr += A0.x * A1.x + A0.y * A1.y;
            ci += A0.x * A1.y - A0.y * A1.x;
            zz += (A0.x * A0.x + A0.y * A0.y) - (A1.x * A1.x + A1.y * A1.y);
          }
        }
      } else {
        int xm = 1 << (p - 4);
        bool up = (lane >> (p - 4)) & 1;
#pragma unroll
        for (int r = 0; r < 16; ++r) {
          float wx = __shfl_xor(a[r].x, xm, 64);
          float wy = __shfl_xor(a[r].y, xm, 64);
          float n2 = a[r].x * a[r].x + a[r].y * a[r].y;
          if (!up) {
            cr += a[r].x * wx + a[r].y * wy;
            ci += a[r].x * wy - a[r].y * wx;
            zz += n2;
          } else {
            zz -= n2;
          }
        }
      }
      obs[i] = 2.f * cr;
      obs[10 + i] = 2.f * ci;
      obs[20 + i] = zz;
    }
#pragma unroll
    for (int j = 0; j < 30; ++j) {
      float vv = obs[j];
      for (int off = 32; off; off >>= 1) vv += __shfl_down(vv, off, 64);
      if (lane == 0) atomicAdd(&sv[b * 30 + j], vv);
    }
  }

  // ---- phase 5: last-arriving block of group b computes its output row ----
  int lastflag = 0;
  if (lane == 0) {
    unsigned old = __hip_atomic_fetch_add(&g_gb[b].done, 1u, __ATOMIC_ACQ_REL,
                                          __HIP_MEMORY_SCOPE_AGENT);
    lastflag = ((old & 15u) == 15u) ? 1 : 0;
  }
  lastflag = __shfl(lastflag, 0, 64);
  if (lastflag) {
    (void)__hip_atomic_load(&g_gb[b].done, __ATOMIC_ACQUIRE, __HIP_MEMORY_SCOPE_AGENT);
    if (lane < 8) {
      float acc = b_out[lane];
#pragma unroll
      for (int j = 0; j < 30; ++j) acc += W_out[lane * 30 + j] * sv[b * 30 + j];
      out[b * 8 + lane] = acc;
    }
  }
}

// ================= fallback multi-kernel path (ws too small) =================

__global__ __launch_bounds__(128) void k_ts(const float* __restrict__ x,
                                            const float* __restrict__ W,
                                            const float* __restrict__ bias,
                                            float2* __restrict__ tsc) {
  int blk = blockIdx.x;
  int b = blk >> 4, t = blk & 15;
  __shared__ float h[64];
  int tid = threadIdx.x;
  if (tid < 64) {
    int f = tid, k = f >> 1;
    float div = expf(-(float)(2 * k) * (logf(10000.f) / 64.f));
    float ang = (float)t * div;
    float pe = (f & 1) ? cosf(ang) : sinf(ang);
    h[f] = x[(b * 64 + f) * 16 + t] + pe;
  }
  __syncthreads();
  if (tid < 80) {
    float acc = bias[tid];
    const float* wr = W + tid * 64;
#pragma unroll 8
    for (int f = 0; f < 64; ++f) acc += h[f] * wr[f];
    float sg = 1.f / (1.f + expf(-acc));
    float s, c;
    sincosf(sg * 3.14159265358979323846f, &s, &c);
    tsc[blk * 80 + tid] = make_float2(s, c);
  }
}

__global__ __launch_bounds__(256) void k_build(const float* __restrict__ prep,
                                               const float* __restrict__ sig,
                                               const float* __restrict__ qffp,
                                               float2* __restrict__ mats,
                                               float2* __restrict__ qsc) {
  __shared__ float2 U[256];
  int tid = threadIdx.x;
  if (tid < 40) {
    float s, c;
    sincosf(0.5f * qffp[tid], &s, &c);
    qsc[tid] = make_float2(s, c);
  }
  U[tid] = make_float2((tid >> 4) == (tid & 15) ? 1.f : 0.f, 0.f);
  __syncthreads();
  for (int ly = 0; ly < 4; ++ly) {
    for (int qi = 0; qi < 4; ++qi) {
      int p = 3 - qi;
      float th = prep[ly * 8 + qi * 2 + 0];
      float s, c;
      sincosf(0.5f * th, &s, &c);
      if (tid < 128) {
        int j = tid & 15, pp = tid >> 4;
        int a0 = insert_zero(pp, p), a1 = a0 | (1 << p);
        float2 u0 = U[a0 * 16 + j], u1 = U[a1 * 16 + j];
        U[a0 * 16 + j] = make_float2(c * u0.x - s * u1.x, c * u0.y - s * u1.y);
        U[a1 * 16 + j] = make_float2(s * u0.x + c * u1.x, s * u0.y + c * u1.y);
      }
      __syncthreads();
      th = prep[ly * 8 + qi * 2 + 1];
      sincosf(0.5f * th, &s, &c);
      if (tid < 128) {
        int j = tid & 15, pp = tid >> 4;
        int a0 = insert_zero(pp, p), a1 = a0 | (1 << p);
        float2 u0 = U[a0 * 16 + j], u1 = U[a1 * 16 + j];
        U[a0 * 16 + j] = make_float2(c * u0.x + s * u0.y, c * u0.y - s * u0.x);
        U[a1 * 16 + j] = make_float2(c * u1.x - s * u1.y, c * u1.y + s * u1.x);
      }
      __syncthreads();
    }
    for (int i = 0; i < 3; ++i) {
      int pc = 3 - i, pt = 2 - i;
      if (tid < 64) {
        int j = tid & 15, pp = tid >> 4;
        int m = insert_zero(pp, pt);
        m = insert_zero(m, pc);
        int a0 = m | (1 << pc), a1 = a0 | (1 << pt);
        float2 t0 = U[a0 * 16 + j], t1 = U[a1 * 16 + j];
        U[a0 * 16 + j] = t1;
        U[a1 * 16 + j] = t0;
      }
      __syncthreads();
    }
  }
  int a = tid >> 4, bb = tid & 15;
  float2 e1, e2, e3;
  sincosf(sig[1], &e1.y, &e1.x);
  sincosf(sig[2], &e2.y, &e2.x);
  sincosf(sig[3], &e3.y, &e3.x);
  float2 acc1 = make_float2(0.f, 0.f), acc2 = make_float2(0.f, 0.f);
  for (int cix = 0; cix < 16; ++cix) {
    float2 t = cmul(U[a * 16 + cix], conj2(U[bb * 16 + cix]));
    acc1 = cfma(t, (cix == 0) ? e1 : conj2(e1), acc1);
    acc2 = cfma(t, (cix == 0) ? e2 : conj2(e2), acc2);
  }
  mats[16 + tid] = acc1;
  mats[272 + tid] = acc2;
  float2 v3 = (a == 0) ? e3 : conj2(e3);
  mats[528 + tid] = cmul(v3, conj2(U[bb * 16 + a]));
  if (tid < 16) {
    float2 e0;
    sincosf(sig[0], &e0.y, &e0.x);
    mats[tid] = cmul(U[tid * 16 + 0], e0);
  }
}

template<bool ADJ, int MODE>
__global__ __launch_bounds__(64) void k_sel(const float2* __restrict__ src,
                                            float2* __restrict__ dst,
                                            const float2* __restrict__ sc_ts,
                                            const float2* __restrict__ mat) {
  int blk = blockIdx.x, lane = threadIdx.x;
  const float2* __restrict__ sc = sc_ts + blk * 80;
  float2 a[16];
  if constexpr (MODE == 0) {
#pragma unroll
    for (int r = 0; r < 16; ++r) a[r] = make_float2(0.f, 0.f);
    if (lane == 0) a[0] = mat[blk & 15];
  } else if constexpr (MODE == 1) {
    const float4* g4 = (const float4*)(src + (size_t)blk * 1024) + lane * 8;
#pragma unroll
    for (int q = 0; q < 8; ++q) {
      float4 v = g4[q];
      a[2 * q]     = make_float2(v.x, v.y);
      a[2 * q + 1] = make_float2(v.z, v.w);
    }
  } else {
    mix_load(a, src, mat, blk >> 4, blk & 15, lane);
  }
  if constexpr (ADJ) {
    run_layer<true>(a, sc + 40, lane);
    run_layer<true>(a, sc, lane);
  } else {
    run_layer<false>(a, sc, lane);
    run_layer<false>(a, sc + 40, lane);
  }
  store_col(dst, blk, lane, a);
}

__global__ __launch_bounds__(64) void k_qff_exp(const float2* __restrict__ src,
                                                const float2* __restrict__ mend,
                                                const float2* __restrict__ qsc,
                                                float* __restrict__ sv) {
  int blk = blockIdx.x, lane = threadIdx.x;
  int b = blk >> 4, aa = blk & 15;
  float2 a[16];
  mix_load(a, src, mend, b, aa, lane);
  run_layer<false>(a, qsc, lane);
  float obs[30];
#pragma unroll
  for (int p = 0; p <= 9; ++p) {
    int i = 9 - p;
    float cr = 0.f, ci = 0.f, zz = 0.f;
    if (p < 4) {
      int m = 1 << p;
#pragma unroll
      for (int r0 = 0; r0 < 16; ++r0) {
        if (!(r0 & m)) {
          float2 A0 = a[r0], A1 = a[r0 | m];
          cr += A0.x * A1.x + A0.y * A1.y;
          ci += A0.x * A1.y - A0.y * A1.x;
          zz += (A0.x * A0.x + A0.y * A0.y) - (A1.x * A1.x + A1.y * A1.y);
        }
      }
    } else {
      int xm = 1 << (p - 4);
      bool up = (lane >> (p - 4)) & 1;
#pragma unroll
      for (int r = 0; r < 16; ++r) {
        float wx = __shfl_xor(a[r].x, xm, 64);
        float wy = __shfl_xor(a[r].y, xm, 64);
        float n2 = a[r].x * a[r].x + a[r].y * a[r].y;
        if (!up) {
          cr += a[r].x * wx + a[r].y * wy;
          ci += a[r].x * wy - a[r].y * wx;
          zz += n2;
        } else {
          zz -= n2;
        }
      }
    }
    obs[i] = 2.f * cr;
    obs[10 + i] = 2.f * ci;
    obs[20 + i] = zz;
  }
#pragma unroll
  for (int j = 0; j < 30; ++j) {
    float v = obs[j];
    for (int off = 32; off; off >>= 1) v += __shfl_down(v, off, 64);
    if (lane == 0) atomicAdd(&sv[b * 30 + j], v);
  }
}

__global__ __launch_bounds__(128) void k_out(const float* __restrict__ sv,
                                             const float* __restrict__ W,
                                             const float* __restrict__ bo,
                                             float* __restrict__ out) {
  int tid = threadIdx.x;
  int b = tid >> 3, o = tid & 7;
  float acc = bo[o];
#pragma unroll
  for (int j = 0; j < 30; ++j) acc += W[o * 30 + j] * sv[b * 30 + j];
  out[tid] = acc;
}

__global__ __launch_bounds__(256) void k_anc(float2* __restrict__ state,
                                             const float2* __restrict__ M) {
  __shared__ float2 sM[256];
  int tid = threadIdx.x;
  sM[tid] = M[tid];
  __syncthreads();
  int t = blockIdx.x * 256 + tid;
  int b = t >> 10, n = t & 1023;
  float2* p = state + b * 16384 + n;
  float2 v[16];
#pragma unroll
  for (int ap = 0; ap < 16; ++ap) v[ap] = p[ap << 10];
#pragma unroll
  for (int ao = 0; ao < 16; ++ao) {
    float re = 0.f, im = 0.f;
#pragma unroll
    for (int ap = 0; ap < 16; ++ap) {
      float2 m = sM[ao * 16 + ap];
      re += m.x * v[ap].x - m.y * v[ap].y;
      im += m.x * v[ap].y + m.y * v[ap].x;
    }
    p[ao << 10] = make_float2(re, im);
  }
}

extern "C" void kernel_launch(void* const* d_in, const int* in_sizes, int n_in,
                              void* d_out, int out_size, void* d_ws, size_t ws_size,
                              hipStream_t stream) {
  const float* x     = (const float*)d_in[0];
  const float* W_fp  = (const float*)d_in[1];
  const float* b_fp  = (const float*)d_in[2];
  const float* prep  = (const float*)d_in[3];
  const float* sig   = (const float*)d_in[4];
  const float* qff   = (const float*)d_in[5];
  const float* W_out = (const float*)d_in[6];
  const float* b_out = (const float*)d_in[7];
  float* out = (float*)d_out;

  char* ws = (char*)d_ws;
  const size_t SZ_STATE = 2097152;      // 256 cols * 512 float4 * 16 B
  const size_t SZ_SV    = 1920;         // 16*30 float

  if (ws_size >= 2 * SZ_STATE + SZ_SV) {
    // fused single-dispatch path (normal launch; per-b group barriers inside)
    float4* part1 = (float4*)ws;
    float4* part2 = (float4*)(ws + SZ_STATE);
    float*  sv    = (float*)(ws + 2 * SZ_STATE);
    k_fused<<<dim3(256), dim3(64), 0, stream>>>(x, W_fp, b_fp, prep, sig, qff,
                                                W_out, b_out, out, part1, part2, sv);
    return;
  }

  // fallback multi-kernel path (original structure)
  const size_t SZ_TSC   = 163840;
  const size_t SZ_MATS  = 6272;
  const size_t SZ_QSC   = 320;
  bool pp = ws_size >= 2 * SZ_STATE + SZ_TSC + SZ_MATS + SZ_QSC + SZ_SV;

  float2* state0 = (float2*)ws;
  float2* state1 = pp ? (float2*)(ws + SZ_STATE) : nullptr;
  char* tail = ws + (pp ? 2 * SZ_STATE : SZ_STATE);
  float2* tsc  = (float2*)tail;
  float2* mats = (float2*)(tail + SZ_TSC);
  float2* qsc  = (float2*)(tail + SZ_TSC + SZ_MATS);
  float*  sv   = (float*) (tail + SZ_TSC + SZ_MATS + SZ_QSC);

  hipMemsetAsync(sv, 0, SZ_SV, stream);
  k_ts<<<256, 128, 0, stream>>>(x, W_fp, b_fp, tsc);
  k_build<<<1, 256, 0, stream>>>(prep, sig, qff, mats, qsc);

  if (pp) {
    k_sel<false, 0><<<256, 64, 0, stream>>>(nullptr, state0, tsc, mats);
    k_sel<true,  2><<<256, 64, 0, stream>>>(state0, state1, tsc, mats + 16);
    k_sel<false, 2><<<256, 64, 0, stream>>>(state1, state0, tsc, mats + 272);
  } else {
    k_sel<false, 0><<<256, 64, 0, stream>>>(nullptr, state0, tsc, mats);
    k_anc<<<64, 256, 0, stream>>>(state0, mats + 16);
    k_sel<true,  1><<<256, 64, 0, stream>>>(state0, state0, tsc, nullptr);
    k_anc<<<64, 256, 0, stream>>>(state0, mats + 272);
    k_sel<false, 1><<<256, 64, 0, stream>>>(state0, state0, tsc, nullptr);
  }
  k_qff_exp<<<256, 64, 0, stream>>>(state0, mats + 528, qsc, sv);
  k_out<<<1, 128, 0, stream>>>(sv, W_out, b_out, out);
}